// Round 4
// baseline (317.322 us; speedup 1.0000x reference)
//
#include <hip/hip_runtime.h>
#include <math.h>

#define HEADS 8
#define HID 256
#define INC 128
#define GDIM 2048  // HEADS*HID
#define NEG_SLOPE 0.2f

typedef unsigned short ushort_t;
typedef short bf16x8 __attribute__((ext_vector_type(8)));
typedef ushort_t u16x8 __attribute__((ext_vector_type(8)));
typedef float f32x4 __attribute__((ext_vector_type(4)));

__device__ __forceinline__ ushort_t f2bf(float f) {
  union { float f; unsigned u; } v; v.f = f;
  unsigned r = (v.u + 0x7FFF + ((v.u >> 16) & 1)) >> 16;  // RTNE
  return (ushort_t)r;
}
__device__ __forceinline__ float bf2f(ushort_t u) {
  union { unsigned u; float f; } v; v.u = ((unsigned)u) << 16;
  return v.f;
}

__device__ __forceinline__ void gload_lds16(const ushort_t* g, ushort_t* l) {
  __builtin_amdgcn_global_load_lds(
      (const __attribute__((address_space(1))) unsigned int*)g,
      (__attribute__((address_space(3))) unsigned int*)l, 16, 0, 0);
}

// LDS chunk swizzle: 16B chunk at (row, c) holds global chunk (c - (row>>1)) & 3.
// Staging (dest = base + lane*16, slot_row = lane>>2, lds_chunk = lane&3):
//   global source chunk for this lane = ((lane&3) - ((lane>>3)&3)) & 3
// Read of global chunk kg from row r: lds chunk = (kg + ((r>>1)&3)) & 3.
__device__ __forceinline__ int src_chunk(int lane) {
  return ((lane & 3) - ((lane >> 3) & 3)) & 3;
}
__device__ __forceinline__ int rd_chunk(int lc, int kg) {
  return (kg + ((lc >> 1) & 3)) & 3;
}

// ---------------- fp32 -> bf16 elementwise ----------------
__global__ __launch_bounds__(256) void f32_to_bf16(
    const float* __restrict__ src, ushort_t* __restrict__ dst, int n)
{
  int i = blockIdx.x * 256 + threadIdx.x;
  if (i < n) dst[i] = f2bf(src[i]);
}

// ---------------- fp32 [R][C] -> bf16 transpose dst[(rowOff+c)*R + r] ----------------
__global__ __launch_bounds__(256) void transpose_f32_bf16(
    const float* __restrict__ src, ushort_t* __restrict__ dst, int R, int C, int rowOff)
{
  __shared__ float tile[32][33];
  int tx = threadIdx.x & 31, ty = threadIdx.x >> 5;  // ty 0..7
  int r0 = blockIdx.x * 32, c0 = blockIdx.y * 32;
  #pragma unroll
  for (int i = 0; i < 32; i += 8) {
    int r = r0 + ty + i, c = c0 + tx;
    if (r < R && c < C) tile[ty + i][tx] = src[(size_t)r * C + c];
  }
  __syncthreads();
  #pragma unroll
  for (int i = 0; i < 32; i += 8) {
    int c = c0 + ty + i, r = r0 + tx;
    if (r < R && c < C) dst[(size_t)(rowOff + c) * R + r] = f2bf(tile[tx][ty + i]);
  }
}

// ---------------- GAT GEMM: hb = bf16(x @ W_gat), fused attention dots ----------------
__global__ __launch_bounds__(256) void gemm_gat(
    const ushort_t* __restrict__ A, const ushort_t* __restrict__ BT,
    ushort_t* __restrict__ hb, float* __restrict__ a_src, float* __restrict__ a_dst,
    const float* __restrict__ att_s, const float* __restrict__ att_d,
    int M, int Nc, int K)
{
  __shared__ ushort_t As[128][32];
  __shared__ ushort_t Bs[128][32];
  int tid = threadIdx.x;
  int wave = tid >> 6, lane = tid & 63;
  int row0 = blockIdx.x * 128, col0 = blockIdx.y * 128;
  int wr = (wave >> 1) * 64, wc = (wave & 1) * 64;
  int lc = lane & 15, kg = lane >> 4;
  int sc = src_chunk(lane);

  f32x4 acc[4][4] = {};

  for (int kt = 0; kt < K; kt += 32) {
    #pragma unroll
    for (int c = 0; c < 2; ++c) {
      int r = c * 64 + wave * 16 + (lane >> 2);
      int ga = row0 + r; if (ga >= M) ga = M - 1;
      gload_lds16(A + (size_t)ga * K + kt + sc * 8, &As[c * 64 + wave * 16][0]);
      int gb = col0 + r;
      gload_lds16(BT + (size_t)gb * K + kt + sc * 8, &Bs[c * 64 + wave * 16][0]);
    }
    __syncthreads();

    bf16x8 af[4], bfr[4];
    #pragma unroll
    for (int mi = 0; mi < 4; ++mi) af[mi] = *(const bf16x8*)&As[wr + mi * 16 + lc][rd_chunk(lc, kg) * 8];
    #pragma unroll
    for (int ni = 0; ni < 4; ++ni) bfr[ni] = *(const bf16x8*)&Bs[wc + ni * 16 + lc][rd_chunk(lc, kg) * 8];
    #pragma unroll
    for (int mi = 0; mi < 4; ++mi)
      #pragma unroll
      for (int ni = 0; ni < 4; ++ni)
        acc[mi][ni] = __builtin_amdgcn_mfma_f32_16x16x32_bf16(af[mi], bfr[ni], acc[mi][ni], 0, 0, 0);
    __syncthreads();
  }

  // epilogue: bf16 store + attention partial dots
  int head = (col0 + wc) >> 8;  // 64-col wave range never crosses a 256-col head
  float as_v[4], ad_v[4];
  #pragma unroll
  for (int ni = 0; ni < 4; ++ni) {
    int gc = col0 + wc + ni * 16 + lc;
    as_v[ni] = att_s[gc];
    ad_v[ni] = att_d[gc];
  }
  #pragma unroll
  for (int mi = 0; mi < 4; ++mi) {
    #pragma unroll
    for (int r = 0; r < 4; ++r) {
      int grow = row0 + wr + mi * 16 + kg * 4 + r;
      float ps = 0.f, pd = 0.f;
      #pragma unroll
      for (int ni = 0; ni < 4; ++ni) {
        float v = acc[mi][ni][r];
        ps += v * as_v[ni];
        pd += v * ad_v[ni];
        if (grow < M) hb[(size_t)grow * Nc + col0 + wc + ni * 16 + lc] = f2bf(v);
      }
      #pragma unroll
      for (int off = 8; off >= 1; off >>= 1) {
        ps += __shfl_xor(ps, off);
        pd += __shfl_xor(pd, off);
      }
      if (lc == 0 && grow < M) {
        atomicAdd(&a_src[grow * 8 + head], ps);
        atomicAdd(&a_dst[grow * 8 + head], pd);
      }
    }
  }
}

// ---------------- split-K bf16 MFMA GEMM: C += A[:, k0:k0+Klen] * BT[:, k0:..]^T ----------------
__global__ __launch_bounds__(256) void gemm_bf16_sk(
    const ushort_t* __restrict__ A, const ushort_t* __restrict__ BT,
    float* __restrict__ C, int M, int Nc, int K, int Klen)
{
  __shared__ ushort_t As[128][32];
  __shared__ ushort_t Bs[128][32];
  int tid = threadIdx.x;
  int wave = tid >> 6, lane = tid & 63;
  int row0 = blockIdx.x * 128, col0 = blockIdx.y * 128;
  int k0 = blockIdx.z * Klen;
  int wr = (wave >> 1) * 64, wc = (wave & 1) * 64;
  int lc = lane & 15, kg = lane >> 4;
  int sc = src_chunk(lane);

  f32x4 acc[4][4] = {};

  for (int kt = k0; kt < k0 + Klen; kt += 32) {
    #pragma unroll
    for (int c = 0; c < 2; ++c) {
      int r = c * 64 + wave * 16 + (lane >> 2);
      int ga = row0 + r; if (ga >= M) ga = M - 1;
      gload_lds16(A + (size_t)ga * K + kt + sc * 8, &As[c * 64 + wave * 16][0]);
      int gb = col0 + r;
      gload_lds16(BT + (size_t)gb * K + kt + sc * 8, &Bs[c * 64 + wave * 16][0]);
    }
    __syncthreads();

    bf16x8 af[4], bfr[4];
    #pragma unroll
    for (int mi = 0; mi < 4; ++mi) af[mi] = *(const bf16x8*)&As[wr + mi * 16 + lc][rd_chunk(lc, kg) * 8];
    #pragma unroll
    for (int ni = 0; ni < 4; ++ni) bfr[ni] = *(const bf16x8*)&Bs[wc + ni * 16 + lc][rd_chunk(lc, kg) * 8];
    #pragma unroll
    for (int mi = 0; mi < 4; ++mi)
      #pragma unroll
      for (int ni = 0; ni < 4; ++ni)
        acc[mi][ni] = __builtin_amdgcn_mfma_f32_16x16x32_bf16(af[mi], bfr[ni], acc[mi][ni], 0, 0, 0);
    __syncthreads();
  }

  #pragma unroll
  for (int mi = 0; mi < 4; ++mi) {
    #pragma unroll
    for (int r = 0; r < 4; ++r) {
      int grow = row0 + wr + mi * 16 + kg * 4 + r;
      if (grow < M) {
        #pragma unroll
        for (int ni = 0; ni < 4; ++ni)
          atomicAdd(&C[(size_t)grow * Nc + col0 + wc + ni * 16 + lc], acc[mi][ni][r]);
      }
    }
  }
}

// ---------------- CSR build ----------------
__global__ void deg_count(const int* __restrict__ ei, int* __restrict__ deg, int E)
{
  int e = blockIdx.x * 256 + threadIdx.x;
  if (e < E) atomicAdd(&deg[ei[E + e]], 1);
}

// exclusive scan; writes start[] and cursor[] (=start)
__global__ __launch_bounds__(256) void scan_deg(const int* __restrict__ deg, int* __restrict__ start,
                                                int* __restrict__ cursor, int N)
{
  __shared__ int sums[256];
  int t = threadIdx.x;
  int chunk = (N + 255) / 256;
  int s = 0;
  for (int i = 0; i < chunk; ++i) {
    int idx = t * chunk + i;
    if (idx < N) s += deg[idx];
  }
  sums[t] = s;
  __syncthreads();
  for (int off = 1; off < 256; off <<= 1) {
    int v = (t >= off) ? sums[t - off] : 0;
    __syncthreads();
    sums[t] += v;
    __syncthreads();
  }
  int run = (t == 0) ? 0 : sums[t - 1];
  for (int i = 0; i < chunk; ++i) {
    int idx = t * chunk + i;
    if (idx < N) { start[idx] = run; cursor[idx] = run; run += deg[idx]; }
  }
}

__global__ void fill_buckets(const int* __restrict__ ei, int* __restrict__ cursor,
                             int* __restrict__ slot, int E)
{
  int e = blockIdx.x * 256 + threadIdx.x;
  if (e < E) {
    int n = ei[E + e];
    int p = atomicAdd(&cursor[n], 1);
    slot[p] = e;
  }
}

// ---------------- GAT per-dst softmax + aggregate (bf16 gather) -> x1 (bf16) ----------------
__global__ __launch_bounds__(256) void gat_aggregate(
    const ushort_t* __restrict__ hb, const float* __restrict__ a_src, const float* __restrict__ a_dst,
    const int* __restrict__ ei, const int* __restrict__ start, const int* __restrict__ deg,
    const int* __restrict__ slot, const float* __restrict__ b_gat, ushort_t* __restrict__ x1,
    int N, int E)
{
  int n = blockIdx.x, t = threadIdx.x;
  __shared__ float adst[8];
  __shared__ float emax[8];
  __shared__ float esum[8];
  __shared__ float red[256];
  __shared__ float alpha_s[32][8];
  __shared__ int src_s[32];
  int cnt = deg[n];
  int base = start[n];
  if (t < 8) adst[t] = a_dst[n * 8 + t];
  __syncthreads();
  int hd = t & 7, lj = t >> 3;
  // phase A: per-head max
  float m = -1e30f;
  for (int j = lj; j < cnt; j += 32) {
    int s = ei[slot[base + j]];
    float v = a_src[s * 8 + hd] + adst[hd];
    v = v > 0.f ? v : NEG_SLOPE * v;
    m = fmaxf(m, v);
  }
  red[t] = m;
  __syncthreads();
  #pragma unroll
  for (int off = 128; off >= 8; off >>= 1) {
    if (t < off) red[t] = fmaxf(red[t], red[t + off]);
    __syncthreads();
  }
  if (t < 8) emax[t] = red[t];
  __syncthreads();
  // phase B: per-head sum of exp
  float ssum = 0.f;
  for (int j = lj; j < cnt; j += 32) {
    int s = ei[slot[base + j]];
    float v = a_src[s * 8 + hd] + adst[hd];
    v = v > 0.f ? v : NEG_SLOPE * v;
    ssum += expf(v - emax[hd]);
  }
  red[t] = ssum;
  __syncthreads();
  #pragma unroll
  for (int off = 128; off >= 8; off >>= 1) {
    if (t < off) red[t] += red[t + off];
    __syncthreads();
  }
  if (t < 8) esum[t] = red[t] + 1e-16f;
  __syncthreads();
  // phase C: thread t owns elements [t*8, t*8+8) -> head = t>>5 constant
  int head = t >> 5;
  float acc[8] = {0.f, 0.f, 0.f, 0.f, 0.f, 0.f, 0.f, 0.f};
  for (int j0 = 0; j0 < cnt; j0 += 32) {
    int j = j0 + lj;
    if (j < cnt) {
      int s = ei[slot[base + j]];
      if (hd == 0) src_s[lj] = s;
      float v = a_src[s * 8 + hd] + adst[hd];
      v = v > 0.f ? v : NEG_SLOPE * v;
      alpha_s[lj][hd] = expf(v - emax[hd]) / esum[hd];
    }
    __syncthreads();
    int lim = cnt - j0; if (lim > 32) lim = 32;
    for (int el = 0; el < lim; ++el) {
      float al = alpha_s[el][head];
      u16x8 v = *(const u16x8*)(hb + (size_t)src_s[el] * GDIM + t * 8);
      #pragma unroll
      for (int i = 0; i < 8; ++i) acc[i] += bf2f(v[i]) * al;
    }
    __syncthreads();
  }
  u16x8 o;
  #pragma unroll
  for (int i = 0; i < 8; ++i) {
    float v = acc[i] + b_gat[t * 8 + i];
    o[i] = f2bf(v > 0.f ? v : 0.f);
  }
  *(u16x8*)(x1 + (size_t)n * GDIM + t * 8) = o;
}

// ---------------- SAGE: mean-aggregate y[:, :256][src] + y[:, 256:] + bias, relu -> x2 ----------------
__global__ __launch_bounds__(256) void sage_aggregate(
    const float* __restrict__ y, const int* __restrict__ ei,
    const int* __restrict__ start, const int* __restrict__ deg, const int* __restrict__ slot,
    const float* __restrict__ b_l, float* __restrict__ x2, int N, int E)
{
  int w = threadIdx.x >> 6, lane = threadIdx.x & 63;
  int n = blockIdx.x * 4 + w;
  if (n >= N) return;
  int cnt = deg[n];
  int base = start[n];
  f32x4 acc = {0.f, 0.f, 0.f, 0.f};
  for (int j = 0; j < cnt; ++j) {
    int s = ei[slot[base + j]];
    f32x4 v = *(const f32x4*)(y + (size_t)s * 512 + lane * 4);
    acc += v;
  }
  float d = (float)cnt; if (d < 1.f) d = 1.f;
  f32x4 root = *(const f32x4*)(y + (size_t)n * 512 + 256 + lane * 4);
  f32x4 b = *(const f32x4*)(b_l + lane * 4);
  f32x4 o;
  #pragma unroll
  for (int i = 0; i < 4; ++i) {
    float v = acc[i] / d + root[i] + b[i];
    o[i] = v > 0.f ? v : 0.f;
  }
  *(f32x4*)(x2 + (size_t)n * HID + lane * 4) = o;
}

// ---------------- MLP head, 16 nodes per block ----------------
__global__ __launch_bounds__(256) void mlp_head(
    const float* __restrict__ x2, const float* __restrict__ W1, const float* __restrict__ b1,
    const float* __restrict__ W2, const float* __restrict__ b2, float* __restrict__ out, int N)
{
  __shared__ float xs[16][256];   // 16 KB
  __shared__ float wred[4][8];
  int t = threadIdx.x;
  int b0 = blockIdx.x * 16;
  for (int i = t; i < 16 * 64; i += 256) {
    int row = i >> 6, c4 = i & 63;
    int gr = b0 + row;
    f32x4 v = (gr < N) ? *(const f32x4*)(x2 + (size_t)gr * HID + c4 * 4)
                       : f32x4{0.f, 0.f, 0.f, 0.f};
    *(f32x4*)&xs[row][c4 * 4] = v;
  }
  __syncthreads();
  int c = t & 127, g = t >> 7;
  float acc[8];
  float bb = b1[c];
  #pragma unroll
  for (int nn = 0; nn < 8; ++nn) acc[nn] = bb;
  for (int k = 0; k < 256; ++k) {
    float w = W1[k * 128 + c];
    #pragma unroll
    for (int nn = 0; nn < 8; ++nn) acc[nn] += xs[g * 8 + nn][k] * w;
  }
  float w2 = W2[c];
  float p[8];
  #pragma unroll
  for (int nn = 0; nn < 8; ++nn) {
    float hm = acc[nn] > 0.f ? acc[nn] : 0.f;
    p[nn] = hm * w2;
  }
  #pragma unroll
  for (int off = 32; off >= 1; off >>= 1)
    #pragma unroll
    for (int nn = 0; nn < 8; ++nn) p[nn] += __shfl_down(p[nn], off);
  int wv = t >> 6;
  if ((t & 63) == 0) {
    #pragma unroll
    for (int nn = 0; nn < 8; ++nn) wred[wv][nn] = p[nn];
  }
  __syncthreads();
  if (t < 16) {
    int gg = t >> 3, nn = t & 7;
    int node = b0 + gg * 8 + nn;
    if (node < N)
      out[node] = wred[gg * 2][nn] + wred[gg * 2 + 1][nn] + b2[0];
  }
}

extern "C" void kernel_launch(void* const* d_in, const int* in_sizes, int n_in,
                              void* d_out, int out_size, void* d_ws, size_t ws_size,
                              hipStream_t stream)
{
  const float* x        = (const float*)d_in[0];
  const int*   ei       = (const int*)d_in[1];
  const float* W_gat    = (const float*)d_in[3];
  const float* att_src  = (const float*)d_in[4];
  const float* att_dst  = (const float*)d_in[5];
  const float* b_gat    = (const float*)d_in[6];
  const float* W_sage_l = (const float*)d_in[7];
  const float* b_sage_l = (const float*)d_in[8];
  const float* W_sage_r = (const float*)d_in[9];
  const float* W_lin1   = (const float*)d_in[10];
  const float* b_lin1   = (const float*)d_in[11];
  const float* W_lin2   = (const float*)d_in[12];
  const float* b_lin2   = (const float*)d_in[13];
  float* out = (float*)d_out;

  const int N = in_sizes[0] / INC;   // 10000
  const int E = in_sizes[1] / 2;     // 80000

  // ---- workspace carve ----
  char* p = (char*)d_ws;
  ushort_t* hb    = (ushort_t*)p;         p += (size_t)N * GDIM * 2;   // 41 MB
  ushort_t* x1b   = (ushort_t*)p;         p += (size_t)N * GDIM * 2;   // 41 MB
  float*    y     = (float*)p;            p += (size_t)N * 512 * 4;    // 20.5 MB
  float*    x2    = (float*)p;            p += (size_t)N * HID * 4;    // 10 MB
  ushort_t* xb    = (ushort_t*)p;         p += (size_t)N * INC * 2;    // 2.6 MB
  ushort_t* WgatT = (ushort_t*)p;         p += (size_t)GDIM * INC * 2; // 0.5 MB
  ushort_t* WsT   = (ushort_t*)p;         p += (size_t)512 * GDIM * 2; // 2 MB
  float*    a_src = (float*)p;            p += (size_t)N * 8 * 4;
  float*    a_dst = (float*)p;            p += (size_t)N * 8 * 4;
  int*      deg   = (int*)p;              p += (size_t)N * 4;
  int*      start = (int*)p;              p += (size_t)N * 4;
  int*      cursor= (int*)p;              p += (size_t)N * 4;
  int*      slot  = (int*)p;              p += (size_t)E * 4;

  hipMemsetAsync(deg, 0, (size_t)N * sizeof(int), stream);
  hipMemsetAsync(a_src, 0, (size_t)N * 8 * sizeof(float), stream);
  hipMemsetAsync(a_dst, 0, (size_t)N * 8 * sizeof(float), stream);
  hipMemsetAsync(y, 0, (size_t)N * 512 * sizeof(float), stream);  // split-K accumulates

  // 0) bf16 conversions / weight transposes
  f32_to_bf16<<<(N * INC + 255) / 256, 256, 0, stream>>>(x, xb, N * INC);
  { dim3 g((INC + 31) / 32, (GDIM + 31) / 32);
    transpose_f32_bf16<<<g, 256, 0, stream>>>(W_gat, WgatT, INC, GDIM, 0); }
  { dim3 g((GDIM + 31) / 32, (HID + 31) / 32);
    transpose_f32_bf16<<<g, 256, 0, stream>>>(W_sage_l, WsT, GDIM, HID, 0);
    transpose_f32_bf16<<<g, 256, 0, stream>>>(W_sage_r, WsT, GDIM, HID, HID); }

  // CSR build (independent of GEMM)
  deg_count<<<(E + 255) / 256, 256, 0, stream>>>(ei, deg, E);
  scan_deg<<<1, 256, 0, stream>>>(deg, start, cursor, N);
  fill_buckets<<<(E + 255) / 256, 256, 0, stream>>>(ei, cursor, slot, E);

  // 1) hb = bf16(x @ W_gat) with fused attention dots
  { dim3 grid((N + 127) / 128, GDIM / 128);
    gemm_gat<<<grid, 256, 0, stream>>>(xb, WgatT, hb, a_src, a_dst, att_src, att_dst,
                                       N, GDIM, INC); }

  // 2) GAT softmax-aggregate -> x1 (bf16)
  gat_aggregate<<<N, 256, 0, stream>>>(hb, a_src, a_dst, ei, start, deg, slot, b_gat, x1b, N, E);

  // 3) y += x1 @ [W_sage_l | W_sage_r]  (split-K=4, fp32 atomic epilogue)
  { dim3 grid((N + 127) / 128, 512 / 128, 4);
    gemm_bf16_sk<<<grid, 256, 0, stream>>>(x1b, WsT, y, N, 512, GDIM, GDIM / 4); }

  // 4) SAGE mean aggregate + relu -> x2
  sage_aggregate<<<(N + 3) / 4, 256, 0, stream>>>(y, ei, start, deg, slot, b_sage_l, x2, N, E);

  // 5) MLP head -> out
  mlp_head<<<(N + 15) / 16, 256, 0, stream>>>(x2, W_lin1, b_lin1, W_lin2, b_lin2, out, N);
}

// Round 5
// 262.861 us; speedup vs baseline: 1.2072x; 1.2072x over previous
//
#include <hip/hip_runtime.h>
#include <math.h>

#define HEADS 8
#define HID 256
#define INC 128
#define GDIM 2048  // HEADS*HID
#define NEG_SLOPE 0.2f

typedef unsigned short ushort_t;
typedef short bf16x8 __attribute__((ext_vector_type(8)));
typedef ushort_t u16x8 __attribute__((ext_vector_type(8)));
typedef float f32x4 __attribute__((ext_vector_type(4)));

__device__ __forceinline__ ushort_t f2bf(float f) {
  union { float f; unsigned u; } v; v.f = f;
  unsigned r = (v.u + 0x7FFF + ((v.u >> 16) & 1)) >> 16;  // RTNE
  return (ushort_t)r;
}
__device__ __forceinline__ float bf2f(ushort_t u) {
  union { unsigned u; float f; } v; v.u = ((unsigned)u) << 16;
  return v.f;
}

__device__ __forceinline__ void gload_lds16(const ushort_t* g, ushort_t* l) {
  __builtin_amdgcn_global_load_lds(
      (const __attribute__((address_space(1))) unsigned int*)g,
      (__attribute__((address_space(3))) unsigned int*)l, 16, 0, 0);
}

// LDS chunk swizzle: 16B chunk at (row, c) holds global chunk (c - (row>>1)) & 3.
// Staging lane: lds_chunk = lane&3, row = lane>>2 -> global chunk = ((lane&3)-((lane>>3)&3))&3
// Read of global chunk kg from frag row lc: lds chunk = (kg + ((lc>>1)&3)) & 3.
__device__ __forceinline__ int src_chunk(int lane) {
  return ((lane & 3) - ((lane >> 3) & 3)) & 3;
}
__device__ __forceinline__ int rd_chunk(int lc, int kg) {
  return (kg + ((lc >> 1) & 3)) & 3;
}

// ---------------- fp32 -> bf16 elementwise ----------------
__global__ __launch_bounds__(256) void f32_to_bf16(
    const float* __restrict__ src, ushort_t* __restrict__ dst, int n)
{
  int i = blockIdx.x * 256 + threadIdx.x;
  if (i < n) dst[i] = f2bf(src[i]);
}

// ---------------- fp32 [R][C] -> bf16 transpose dst[(rowOff+c)*R + r] ----------------
__global__ __launch_bounds__(256) void transpose_f32_bf16(
    const float* __restrict__ src, ushort_t* __restrict__ dst, int R, int C, int rowOff)
{
  __shared__ float tile[32][33];
  int tx = threadIdx.x & 31, ty = threadIdx.x >> 5;  // ty 0..7
  int r0 = blockIdx.x * 32, c0 = blockIdx.y * 32;
  #pragma unroll
  for (int i = 0; i < 32; i += 8) {
    int r = r0 + ty + i, c = c0 + tx;
    if (r < R && c < C) tile[ty + i][tx] = src[(size_t)r * C + c];
  }
  __syncthreads();
  #pragma unroll
  for (int i = 0; i < 32; i += 8) {
    int c = c0 + ty + i, r = r0 + tx;
    if (r < R && c < C) dst[(size_t)(rowOff + c) * R + r] = f2bf(tile[tx][ty + i]);
  }
}

// ---------------- GAT GEMM: hb = bf16(x @ W_gat), fused attention dots ----------------
// 128x128 tile, BK=32, double-buffered LDS prefetch, swizzled staging.
__global__ __launch_bounds__(256) void gemm_gat(
    const ushort_t* __restrict__ A, const ushort_t* __restrict__ BT,
    ushort_t* __restrict__ hb, float* __restrict__ a_src, float* __restrict__ a_dst,
    const float* __restrict__ att_s, const float* __restrict__ att_d,
    int M, int Nc, int K)
{
  __shared__ ushort_t As[2][128][32];
  __shared__ ushort_t Bs[2][128][32];
  int tid = threadIdx.x;
  int wave = tid >> 6, lane = tid & 63;
  int row0 = blockIdx.x * 128, col0 = blockIdx.y * 128;
  int wr = (wave >> 1) * 64, wc = (wave & 1) * 64;
  int lc = lane & 15, kg = lane >> 4;
  int sc = src_chunk(lane), srow = lane >> 2;

  f32x4 acc[4][4] = {};

  #define STAGE_G(buf, kt)                                                        \
    _Pragma("unroll")                                                             \
    for (int c = 0; c < 2; ++c) {                                                 \
      int r = c * 64 + wave * 16 + srow;                                          \
      int ga = row0 + r; if (ga >= M) ga = M - 1;                                 \
      gload_lds16(A + (size_t)ga * K + (kt) + sc * 8, &As[buf][c * 64 + wave * 16][0]); \
      int gb = col0 + r;                                                          \
      gload_lds16(BT + (size_t)gb * K + (kt) + sc * 8, &Bs[buf][c * 64 + wave * 16][0]); \
    }

  #define COMPUTE_G(buf)                                                          \
    {                                                                             \
      bf16x8 af[4], bfr[4];                                                       \
      _Pragma("unroll")                                                           \
      for (int mi = 0; mi < 4; ++mi)                                              \
        af[mi] = *(const bf16x8*)&As[buf][wr + mi * 16 + lc][rd_chunk(lc, kg) * 8]; \
      _Pragma("unroll")                                                           \
      for (int ni = 0; ni < 4; ++ni)                                              \
        bfr[ni] = *(const bf16x8*)&Bs[buf][wc + ni * 16 + lc][rd_chunk(lc, kg) * 8]; \
      _Pragma("unroll")                                                           \
      for (int mi = 0; mi < 4; ++mi)                                              \
        _Pragma("unroll")                                                         \
        for (int ni = 0; ni < 4; ++ni)                                            \
          acc[mi][ni] = __builtin_amdgcn_mfma_f32_16x16x32_bf16(af[mi], bfr[ni], acc[mi][ni], 0, 0, 0); \
    }

  STAGE_G(0, 0);
  __syncthreads();
  int cur = 0;
  for (int kt = 32; kt < K; kt += 32) {
    STAGE_G(cur ^ 1, kt);
    COMPUTE_G(cur);
    __syncthreads();
    cur ^= 1;
  }
  COMPUTE_G(cur);
  #undef STAGE_G
  #undef COMPUTE_G

  // epilogue: bf16 store + attention partial dots
  int head = (col0 + wc) >> 8;  // 64-col wave range never crosses a 256-col head
  float as_v[4], ad_v[4];
  #pragma unroll
  for (int ni = 0; ni < 4; ++ni) {
    int gc = col0 + wc + ni * 16 + lc;
    as_v[ni] = att_s[gc];
    ad_v[ni] = att_d[gc];
  }
  #pragma unroll
  for (int mi = 0; mi < 4; ++mi) {
    #pragma unroll
    for (int r = 0; r < 4; ++r) {
      int grow = row0 + wr + mi * 16 + kg * 4 + r;
      float ps = 0.f, pd = 0.f;
      #pragma unroll
      for (int ni = 0; ni < 4; ++ni) {
        float v = acc[mi][ni][r];
        ps += v * as_v[ni];
        pd += v * ad_v[ni];
        if (grow < M) hb[(size_t)grow * Nc + col0 + wc + ni * 16 + lc] = f2bf(v);
      }
      #pragma unroll
      for (int off = 8; off >= 1; off >>= 1) {
        ps += __shfl_xor(ps, off);
        pd += __shfl_xor(pd, off);
      }
      if (lc == 0 && grow < M) {
        atomicAdd(&a_src[grow * 8 + head], ps);
        atomicAdd(&a_dst[grow * 8 + head], pd);
      }
    }
  }
}

// ---------------- SAGE GEMM: C = A * BT^T, 64x128 tile, dbuf prefetch ----------------
__global__ __launch_bounds__(256) void gemm_sage(
    const ushort_t* __restrict__ A, const ushort_t* __restrict__ BT,
    float* __restrict__ C, int M, int Nc, int K)
{
  __shared__ ushort_t As[2][64][32];   // 4 KB per buffer
  __shared__ ushort_t Bs[2][128][32];  // 8 KB per buffer
  int tid = threadIdx.x;
  int wave = tid >> 6, lane = tid & 63;
  int row0 = blockIdx.x * 64, col0 = blockIdx.y * 128;
  int wr = (wave >> 1) * 32, wc = (wave & 1) * 64;
  int lc = lane & 15, kg = lane >> 4;
  int sc = src_chunk(lane), srow = lane >> 2;

  f32x4 acc[2][4] = {};

  #define STAGE_S(buf, kt)                                                        \
    {                                                                             \
      int r = wave * 16 + srow;                                                   \
      int ga = row0 + r; if (ga >= M) ga = M - 1;                                 \
      gload_lds16(A + (size_t)ga * K + (kt) + sc * 8, &As[buf][wave * 16][0]);    \
      _Pragma("unroll")                                                           \
      for (int c = 0; c < 2; ++c) {                                               \
        int gb = col0 + c * 64 + r;                                               \
        gload_lds16(BT + (size_t)gb * K + (kt) + sc * 8, &Bs[buf][c * 64 + wave * 16][0]); \
      }                                                                           \
    }

  #define COMPUTE_S(buf)                                                          \
    {                                                                             \
      bf16x8 af[2], bfr[4];                                                       \
      _Pragma("unroll")                                                           \
      for (int mi = 0; mi < 2; ++mi)                                              \
        af[mi] = *(const bf16x8*)&As[buf][wr + mi * 16 + lc][rd_chunk(lc, kg) * 8]; \
      _Pragma("unroll")                                                           \
      for (int ni = 0; ni < 4; ++ni)                                              \
        bfr[ni] = *(const bf16x8*)&Bs[buf][wc + ni * 16 + lc][rd_chunk(lc, kg) * 8]; \
      _Pragma("unroll")                                                           \
      for (int mi = 0; mi < 2; ++mi)                                              \
        _Pragma("unroll")                                                         \
        for (int ni = 0; ni < 4; ++ni)                                            \
          acc[mi][ni] = __builtin_amdgcn_mfma_f32_16x16x32_bf16(af[mi], bfr[ni], acc[mi][ni], 0, 0, 0); \
    }

  STAGE_S(0, 0);
  __syncthreads();
  int cur = 0;
  for (int kt = 32; kt < K; kt += 32) {
    STAGE_S(cur ^ 1, kt);
    COMPUTE_S(cur);
    __syncthreads();
    cur ^= 1;
  }
  COMPUTE_S(cur);
  #undef STAGE_S
  #undef COMPUTE_S

  #pragma unroll
  for (int mi = 0; mi < 2; ++mi) {
    #pragma unroll
    for (int r = 0; r < 4; ++r) {
      int grow = row0 + wr + mi * 16 + kg * 4 + r;
      if (grow < M) {
        #pragma unroll
        for (int ni = 0; ni < 4; ++ni)
          C[(size_t)grow * Nc + col0 + wc + ni * 16 + lc] = acc[mi][ni][r];
      }
    }
  }
}

// ---------------- CSR build ----------------
__global__ void deg_count(const int* __restrict__ ei, int* __restrict__ deg, int E)
{
  int e = blockIdx.x * 256 + threadIdx.x;
  if (e < E) atomicAdd(&deg[ei[E + e]], 1);
}

// exclusive scan; writes start[] and cursor[] (=start)
__global__ __launch_bounds__(256) void scan_deg(const int* __restrict__ deg, int* __restrict__ start,
                                                int* __restrict__ cursor, int N)
{
  __shared__ int sums[256];
  int t = threadIdx.x;
  int chunk = (N + 255) / 256;
  int s = 0;
  for (int i = 0; i < chunk; ++i) {
    int idx = t * chunk + i;
    if (idx < N) s += deg[idx];
  }
  sums[t] = s;
  __syncthreads();
  for (int off = 1; off < 256; off <<= 1) {
    int v = (t >= off) ? sums[t - off] : 0;
    __syncthreads();
    sums[t] += v;
    __syncthreads();
  }
  int run = (t == 0) ? 0 : sums[t - 1];
  for (int i = 0; i < chunk; ++i) {
    int idx = t * chunk + i;
    if (idx < N) { start[idx] = run; cursor[idx] = run; run += deg[idx]; }
  }
}

__global__ void fill_buckets(const int* __restrict__ ei, int* __restrict__ cursor,
                             int* __restrict__ slot, int E)
{
  int e = blockIdx.x * 256 + threadIdx.x;
  if (e < E) {
    int n = ei[E + e];
    int p = atomicAdd(&cursor[n], 1);
    slot[p] = e;
  }
}

// ---------------- GAT per-dst softmax + aggregate (bf16 gather) -> x1 (bf16) ----------------
__global__ __launch_bounds__(256) void gat_aggregate(
    const ushort_t* __restrict__ hb, const float* __restrict__ a_src, const float* __restrict__ a_dst,
    const int* __restrict__ ei, const int* __restrict__ start, const int* __restrict__ deg,
    const int* __restrict__ slot, const float* __restrict__ b_gat, ushort_t* __restrict__ x1,
    int N, int E)
{
  int n = blockIdx.x, t = threadIdx.x;
  __shared__ float adst[8];
  __shared__ float emax[8];
  __shared__ float esum[8];
  __shared__ float red[256];
  __shared__ float alpha_s[32][8];
  __shared__ int src_s[32];
  int cnt = deg[n];
  int base = start[n];
  if (t < 8) adst[t] = a_dst[n * 8 + t];
  __syncthreads();
  int hd = t & 7, lj = t >> 3;
  // phase A: per-head max
  float m = -1e30f;
  for (int j = lj; j < cnt; j += 32) {
    int s = ei[slot[base + j]];
    float v = a_src[s * 8 + hd] + adst[hd];
    v = v > 0.f ? v : NEG_SLOPE * v;
    m = fmaxf(m, v);
  }
  red[t] = m;
  __syncthreads();
  #pragma unroll
  for (int off = 128; off >= 8; off >>= 1) {
    if (t < off) red[t] = fmaxf(red[t], red[t + off]);
    __syncthreads();
  }
  if (t < 8) emax[t] = red[t];
  __syncthreads();
  // phase B: per-head sum of exp
  float ssum = 0.f;
  for (int j = lj; j < cnt; j += 32) {
    int s = ei[slot[base + j]];
    float v = a_src[s * 8 + hd] + adst[hd];
    v = v > 0.f ? v : NEG_SLOPE * v;
    ssum += expf(v - emax[hd]);
  }
  red[t] = ssum;
  __syncthreads();
  #pragma unroll
  for (int off = 128; off >= 8; off >>= 1) {
    if (t < off) red[t] += red[t + off];
    __syncthreads();
  }
  if (t < 8) esum[t] = red[t] + 1e-16f;
  __syncthreads();
  // phase C: thread t owns elements [t*8, t*8+8) -> head = t>>5 constant
  int head = t >> 5;
  float acc[8] = {0.f, 0.f, 0.f, 0.f, 0.f, 0.f, 0.f, 0.f};
  for (int j0 = 0; j0 < cnt; j0 += 32) {
    int j = j0 + lj;
    if (j < cnt) {
      int s = ei[slot[base + j]];
      if (hd == 0) src_s[lj] = s;
      float v = a_src[s * 8 + hd] + adst[hd];
      v = v > 0.f ? v : NEG_SLOPE * v;
      alpha_s[lj][hd] = expf(v - emax[hd]) / esum[hd];
    }
    __syncthreads();
    int lim = cnt - j0; if (lim > 32) lim = 32;
    for (int el = 0; el < lim; ++el) {
      float al = alpha_s[el][head];
      u16x8 v = *(const u16x8*)(hb + (size_t)src_s[el] * GDIM + t * 8);
      #pragma unroll
      for (int i = 0; i < 8; ++i) acc[i] += bf2f(v[i]) * al;
    }
    __syncthreads();
  }
  u16x8 o;
  #pragma unroll
  for (int i = 0; i < 8; ++i) {
    float v = acc[i] + b_gat[t * 8 + i];
    o[i] = f2bf(v > 0.f ? v : 0.f);
  }
  *(u16x8*)(x1 + (size_t)n * GDIM + t * 8) = o;
}

// ---------------- SAGE: mean-aggregate y[:, :256][src] + y[:, 256:] + bias, relu -> x2 ----------------
__global__ __launch_bounds__(256) void sage_aggregate(
    const float* __restrict__ y, const int* __restrict__ ei,
    const int* __restrict__ start, const int* __restrict__ deg, const int* __restrict__ slot,
    const float* __restrict__ b_l, float* __restrict__ x2, int N, int E)
{
  int w = threadIdx.x >> 6, lane = threadIdx.x & 63;
  int n = blockIdx.x * 4 + w;
  if (n >= N) return;
  int cnt = deg[n];
  int base = start[n];
  f32x4 acc = {0.f, 0.f, 0.f, 0.f};
  for (int j = 0; j < cnt; ++j) {
    int s = ei[slot[base + j]];
    f32x4 v = *(const f32x4*)(y + (size_t)s * 512 + lane * 4);
    acc += v;
  }
  float d = (float)cnt; if (d < 1.f) d = 1.f;
  f32x4 root = *(const f32x4*)(y + (size_t)n * 512 + 256 + lane * 4);
  f32x4 b = *(const f32x4*)(b_l + lane * 4);
  f32x4 o;
  #pragma unroll
  for (int i = 0; i < 4; ++i) {
    float v = acc[i] / d + root[i] + b[i];
    o[i] = v > 0.f ? v : 0.f;
  }
  *(f32x4*)(x2 + (size_t)n * HID + lane * 4) = o;
}

// ---------------- MLP head, 16 nodes per block ----------------
__global__ __launch_bounds__(256) void mlp_head(
    const float* __restrict__ x2, const float* __restrict__ W1, const float* __restrict__ b1,
    const float* __restrict__ W2, const float* __restrict__ b2, float* __restrict__ out, int N)
{
  __shared__ float xs[16][256];   // 16 KB
  __shared__ float wred[4][8];
  int t = threadIdx.x;
  int b0 = blockIdx.x * 16;
  for (int i = t; i < 16 * 64; i += 256) {
    int row = i >> 6, c4 = i & 63;
    int gr = b0 + row;
    f32x4 v = (gr < N) ? *(const f32x4*)(x2 + (size_t)gr * HID + c4 * 4)
                       : f32x4{0.f, 0.f, 0.f, 0.f};
    *(f32x4*)&xs[row][c4 * 4] = v;
  }
  __syncthreads();
  int c = t & 127, g = t >> 7;
  float acc[8];
  float bb = b1[c];
  #pragma unroll
  for (int nn = 0; nn < 8; ++nn) acc[nn] = bb;
  for (int k = 0; k < 256; ++k) {
    float w = W1[k * 128 + c];
    #pragma unroll
    for (int nn = 0; nn < 8; ++nn) acc[nn] += xs[g * 8 + nn][k] * w;
  }
  float w2 = W2[c];
  float p[8];
  #pragma unroll
  for (int nn = 0; nn < 8; ++nn) {
    float hm = acc[nn] > 0.f ? acc[nn] : 0.f;
    p[nn] = hm * w2;
  }
  #pragma unroll
  for (int off = 32; off >= 1; off >>= 1)
    #pragma unroll
    for (int nn = 0; nn < 8; ++nn) p[nn] += __shfl_down(p[nn], off);
  int wv = t >> 6;
  if ((t & 63) == 0) {
    #pragma unroll
    for (int nn = 0; nn < 8; ++nn) wred[wv][nn] = p[nn];
  }
  __syncthreads();
  if (t < 16) {
    int gg = t >> 3, nn = t & 7;
    int node = b0 + gg * 8 + nn;
    if (node < N)
      out[node] = wred[gg * 2][nn] + wred[gg * 2 + 1][nn] + b2[0];
  }
}

extern "C" void kernel_launch(void* const* d_in, const int* in_sizes, int n_in,
                              void* d_out, int out_size, void* d_ws, size_t ws_size,
                              hipStream_t stream)
{
  const float* x        = (const float*)d_in[0];
  const int*   ei       = (const int*)d_in[1];
  const float* W_gat    = (const float*)d_in[3];
  const float* att_src  = (const float*)d_in[4];
  const float* att_dst  = (const float*)d_in[5];
  const float* b_gat    = (const float*)d_in[6];
  const float* W_sage_l = (const float*)d_in[7];
  const float* b_sage_l = (const float*)d_in[8];
  const float* W_sage_r = (const float*)d_in[9];
  const float* W_lin1   = (const float*)d_in[10];
  const float* b_lin1   = (const float*)d_in[11];
  const float* W_lin2   = (const float*)d_in[12];
  const float* b_lin2   = (const float*)d_in[13];
  float* out = (float*)d_out;

  const int N = in_sizes[0] / INC;   // 10000
  const int E = in_sizes[1] / 2;     // 80000

  // ---- workspace carve ----
  char* p = (char*)d_ws;
  ushort_t* hb    = (ushort_t*)p;         p += (size_t)N * GDIM * 2;   // 41 MB
  ushort_t* x1b   = (ushort_t*)p;         p += (size_t)N * GDIM * 2;   // 41 MB
  float*    y     = (float*)p;            p += (size_t)N * 512 * 4;    // 20.5 MB
  float*    x2    = (float*)p;            p += (size_t)N * HID * 4;    // 10 MB
  ushort_t* xb    = (ushort_t*)p;         p += (size_t)N * INC * 2;    // 2.6 MB
  ushort_t* WgatT = (ushort_t*)p;         p += (size_t)GDIM * INC * 2; // 0.5 MB
  ushort_t* WsT   = (ushort_t*)p;         p += (size_t)512 * GDIM * 2; // 2 MB
  float*    a_src = (float*)p;            p += (size_t)N * 8 * 4;
  float*    a_dst = (float*)p;            p += (size_t)N * 8 * 4;
  int*      deg   = (int*)p;              p += (size_t)N * 4;
  int*      start = (int*)p;              p += (size_t)N * 4;
  int*      cursor= (int*)p;              p += (size_t)N * 4;
  int*      slot  = (int*)p;              p += (size_t)E * 4;

  hipMemsetAsync(deg, 0, (size_t)N * sizeof(int), stream);
  hipMemsetAsync(a_src, 0, (size_t)N * 8 * sizeof(float), stream);
  hipMemsetAsync(a_dst, 0, (size_t)N * 8 * sizeof(float), stream);

  // 0) bf16 conversions / weight transposes
  f32_to_bf16<<<(N * INC + 255) / 256, 256, 0, stream>>>(x, xb, N * INC);
  { dim3 g((INC + 31) / 32, (GDIM + 31) / 32);
    transpose_f32_bf16<<<g, 256, 0, stream>>>(W_gat, WgatT, INC, GDIM, 0); }
  { dim3 g((GDIM + 31) / 32, (HID + 31) / 32);
    transpose_f32_bf16<<<g, 256, 0, stream>>>(W_sage_l, WsT, GDIM, HID, 0);
    transpose_f32_bf16<<<g, 256, 0, stream>>>(W_sage_r, WsT, GDIM, HID, HID); }

  // CSR build (independent of GEMM)
  deg_count<<<(E + 255) / 256, 256, 0, stream>>>(ei, deg, E);
  scan_deg<<<1, 256, 0, stream>>>(deg, start, cursor, N);
  fill_buckets<<<(E + 255) / 256, 256, 0, stream>>>(ei, cursor, slot, E);

  // 1) hb = bf16(x @ W_gat) with fused attention dots
  { dim3 grid((N + 127) / 128, GDIM / 128);
    gemm_gat<<<grid, 256, 0, stream>>>(xb, WgatT, hb, a_src, a_dst, att_src, att_dst,
                                       N, GDIM, INC); }

  // 2) GAT softmax-aggregate -> x1 (bf16)
  gat_aggregate<<<N, 256, 0, stream>>>(hb, a_src, a_dst, ei, start, deg, slot, b_gat, x1b, N, E);

  // 3) y = x1 @ [W_sage_l | W_sage_r]  (64x128 tile, dbuf prefetch)
  { dim3 grid((N + 63) / 64, 512 / 128);
    gemm_sage<<<grid, 256, 0, stream>>>(x1b, WsT, y, N, 512, GDIM); }

  // 4) SAGE mean aggregate + relu -> x2
  sage_aggregate<<<(N + 3) / 4, 256, 0, stream>>>(y, ei, start, deg, slot, b_sage_l, x2, N, E);

  // 5) MLP head -> out
  mlp_head<<<(N + 15) / 16, 256, 0, stream>>>(x2, W_lin1, b_lin1, W_lin2, b_lin2, out, N);
}

// Round 6
// 226.801 us; speedup vs baseline: 1.3991x; 1.1590x over previous
//
#include <hip/hip_runtime.h>
#include <math.h>

#define HEADS 8
#define HID 256
#define INC 128
#define GDIM 2048  // HEADS*HID
#define NEG_SLOPE 0.2f

typedef unsigned short ushort_t;
typedef short bf16x8 __attribute__((ext_vector_type(8)));
typedef ushort_t u16x8 __attribute__((ext_vector_type(8)));
typedef float f32x4 __attribute__((ext_vector_type(4)));

__device__ __forceinline__ ushort_t f2bf(float f) {
  union { float f; unsigned u; } v; v.f = f;
  unsigned r = (v.u + 0x7FFF + ((v.u >> 16) & 1)) >> 16;  // RTNE
  return (ushort_t)r;
}
__device__ __forceinline__ float bf2f(ushort_t u) {
  union { unsigned u; float f; } v; v.u = ((unsigned)u) << 16;
  return v.f;
}

__device__ __forceinline__ void gload_lds16(const ushort_t* g, ushort_t* l) {
  __builtin_amdgcn_global_load_lds(
      (const __attribute__((address_space(1))) unsigned int*)g,
      (__attribute__((address_space(3))) unsigned int*)l, 16, 0, 0);
}

// LDS chunk swizzle (verified r4/r5: SQ_LDS_BANK_CONFLICT -> 0)
__device__ __forceinline__ int src_chunk(int lane) {
  return ((lane & 3) - ((lane >> 3) & 3)) & 3;
}
__device__ __forceinline__ int rd_chunk(int lc, int kg) {
  return (kg + ((lc >> 1) & 3)) & 3;
}

// ---------------- fused prep: x->bf16, 3 weight transposes, deg_count, zero a ----------------
__global__ __launch_bounds__(256) void prep(
    const float* __restrict__ x, ushort_t* __restrict__ xb,
    const float* __restrict__ Wg, ushort_t* __restrict__ WgT,
    const float* __restrict__ Wl, const float* __restrict__ Wr, ushort_t* __restrict__ WsT,
    const int* __restrict__ ei, int* __restrict__ deg, int E,
    float* __restrict__ az, int nAZ,
    int o1, int o2, int o3, int o4, int o5)
{
  __shared__ float tile[32][33];
  int b = blockIdx.x, t = threadIdx.x;
  if (b < o1) {
    // x -> bf16, 1024 elems/block (exact: N*INC % 1024 == 0)
    int i = b * 1024 + t * 4;
    float4 v = *(const float4*)(x + i);
    ushort_t o[4] = {f2bf(v.x), f2bf(v.y), f2bf(v.z), f2bf(v.w)};
    *(unsigned long long*)(xb + i) = *(unsigned long long*)o;
  } else if (b < o4) {
    // transposes (all dims multiples of 32)
    const float* src; ushort_t* dst; int R, C, rowOff, bx, by;
    if (b < o2)      { int idx = b - o1; src = Wg; dst = WgT; R = INC;  C = GDIM; rowOff = 0;   bx = idx % (INC / 32);  by = idx / (INC / 32); }
    else if (b < o3) { int idx = b - o2; src = Wl; dst = WsT; R = GDIM; C = HID;  rowOff = 0;   bx = idx % (GDIM / 32); by = idx / (GDIM / 32); }
    else             { int idx = b - o3; src = Wr; dst = WsT; R = GDIM; C = HID;  rowOff = HID; bx = idx % (GDIM / 32); by = idx / (GDIM / 32); }
    int tx = t & 31, ty = t >> 5;
    int r0 = bx * 32, c0 = by * 32;
    #pragma unroll
    for (int i = 0; i < 32; i += 8)
      tile[ty + i][tx] = src[(size_t)(r0 + ty + i) * C + c0 + tx];
    __syncthreads();
    #pragma unroll
    for (int i = 0; i < 32; i += 8)
      dst[(size_t)(rowOff + c0 + ty + i) * R + r0 + tx] = f2bf(tile[tx][ty + i]);
  } else if (b < o5) {
    int e = (b - o4) * 256 + t;
    if (e < E) atomicAdd(&deg[ei[E + e]], 1);
  } else {
    int i = (b - o5) * 1024 + t * 4;
    if (i < nAZ) *(f32x4*)(az + i) = f32x4{0.f, 0.f, 0.f, 0.f};
  }
}

// ---------------- GAT GEMM: hb = bf16(x @ W_gat), fused attention dots ----------------
__global__ __launch_bounds__(256) void gemm_gat(
    const ushort_t* __restrict__ A, const ushort_t* __restrict__ BT,
    ushort_t* __restrict__ hb, float* __restrict__ a_src, float* __restrict__ a_dst,
    const float* __restrict__ att_s, const float* __restrict__ att_d,
    int M, int Nc, int K)
{
  __shared__ ushort_t As[2][128][32];
  __shared__ ushort_t Bs[2][128][32];
  int tid = threadIdx.x;
  int wave = tid >> 6, lane = tid & 63;
  int row0 = blockIdx.x * 128, col0 = blockIdx.y * 128;
  int wr = (wave >> 1) * 64, wc = (wave & 1) * 64;
  int lc = lane & 15, kg = lane >> 4;
  int sc = src_chunk(lane), srow = lane >> 2;

  f32x4 acc[4][4] = {};

  #define STAGE_G(buf, kt)                                                        \
    _Pragma("unroll")                                                             \
    for (int c = 0; c < 2; ++c) {                                                 \
      int r = c * 64 + wave * 16 + srow;                                          \
      int ga = row0 + r; if (ga >= M) ga = M - 1;                                 \
      gload_lds16(A + (size_t)ga * K + (kt) + sc * 8, &As[buf][c * 64 + wave * 16][0]); \
      int gb = col0 + r;                                                          \
      gload_lds16(BT + (size_t)gb * K + (kt) + sc * 8, &Bs[buf][c * 64 + wave * 16][0]); \
    }

  #define COMPUTE_G(buf)                                                          \
    {                                                                             \
      bf16x8 af[4], bfr[4];                                                       \
      _Pragma("unroll")                                                           \
      for (int mi = 0; mi < 4; ++mi)                                              \
        af[mi] = *(const bf16x8*)&As[buf][wr + mi * 16 + lc][rd_chunk(lc, kg) * 8]; \
      _Pragma("unroll")                                                           \
      for (int ni = 0; ni < 4; ++ni)                                              \
        bfr[ni] = *(const bf16x8*)&Bs[buf][wc + ni * 16 + lc][rd_chunk(lc, kg) * 8]; \
      _Pragma("unroll")                                                           \
      for (int mi = 0; mi < 4; ++mi)                                              \
        _Pragma("unroll")                                                         \
        for (int ni = 0; ni < 4; ++ni)                                            \
          acc[mi][ni] = __builtin_amdgcn_mfma_f32_16x16x32_bf16(af[mi], bfr[ni], acc[mi][ni], 0, 0, 0); \
    }

  STAGE_G(0, 0);
  __syncthreads();
  int cur = 0;
  for (int kt = 32; kt < K; kt += 32) {
    STAGE_G(cur ^ 1, kt);
    COMPUTE_G(cur);
    __syncthreads();
    cur ^= 1;
  }
  COMPUTE_G(cur);
  #undef STAGE_G
  #undef COMPUTE_G

  // epilogue: bf16 store + attention partial dots
  int head = (col0 + wc) >> 8;
  float as_v[4], ad_v[4];
  #pragma unroll
  for (int ni = 0; ni < 4; ++ni) {
    int gc = col0 + wc + ni * 16 + lc;
    as_v[ni] = att_s[gc];
    ad_v[ni] = att_d[gc];
  }
  #pragma unroll
  for (int mi = 0; mi < 4; ++mi) {
    #pragma unroll
    for (int r = 0; r < 4; ++r) {
      int grow = row0 + wr + mi * 16 + kg * 4 + r;
      float ps = 0.f, pd = 0.f;
      #pragma unroll
      for (int ni = 0; ni < 4; ++ni) {
        float v = acc[mi][ni][r];
        ps += v * as_v[ni];
        pd += v * ad_v[ni];
        if (grow < M) hb[(size_t)grow * Nc + col0 + wc + ni * 16 + lc] = f2bf(v);
      }
      #pragma unroll
      for (int off = 8; off >= 1; off >>= 1) {
        ps += __shfl_xor(ps, off);
        pd += __shfl_xor(pd, off);
      }
      if (lc == 0 && grow < M) {
        atomicAdd(&a_src[grow * 8 + head], ps);
        atomicAdd(&a_dst[grow * 8 + head], pd);
      }
    }
  }
}

// ---------------- SAGE GEMM: C = A * BT^T, 64x256 tile, 8 waves, dbuf ----------------
__global__ __launch_bounds__(512) void gemm_sage(
    const ushort_t* __restrict__ A, const ushort_t* __restrict__ BT,
    float* __restrict__ C, int M, int Nc, int K)
{
  __shared__ ushort_t As[2][64][32];    // 4 KB/buf
  __shared__ ushort_t Bs[2][256][32];   // 16 KB/buf
  int tid = threadIdx.x;
  int wave = tid >> 6, lane = tid & 63;
  int row0 = blockIdx.x * 64, col0 = blockIdx.y * 256;
  int wr = (wave >> 2) * 32, wc = (wave & 3) * 64;
  int lc = lane & 15, kg = lane >> 4;
  int sc = src_chunk(lane), srow = lane >> 2;

  f32x4 acc[2][4] = {};

  #define STAGE_S(buf, kt)                                                        \
    {                                                                             \
      if (wave < 4) {                                                             \
        int ga = row0 + wave * 16 + srow; if (ga >= M) ga = M - 1;                \
        gload_lds16(A + (size_t)ga * K + (kt) + sc * 8, &As[buf][wave * 16][0]);  \
      }                                                                           \
      _Pragma("unroll")                                                           \
      for (int c = 0; c < 2; ++c) {                                               \
        int gb = col0 + c * 128 + wave * 16 + srow;                               \
        gload_lds16(BT + (size_t)gb * K + (kt) + sc * 8, &Bs[buf][c * 128 + wave * 16][0]); \
      }                                                                           \
    }

  #define COMPUTE_S(buf)                                                          \
    {                                                                             \
      bf16x8 af[2], bfr[4];                                                       \
      _Pragma("unroll")                                                           \
      for (int mi = 0; mi < 2; ++mi)                                              \
        af[mi] = *(const bf16x8*)&As[buf][wr + mi * 16 + lc][rd_chunk(lc, kg) * 8]; \
      _Pragma("unroll")                                                           \
      for (int ni = 0; ni < 4; ++ni)                                              \
        bfr[ni] = *(const bf16x8*)&Bs[buf][wc + ni * 16 + lc][rd_chunk(lc, kg) * 8]; \
      _Pragma("unroll")                                                           \
      for (int mi = 0; mi < 2; ++mi)                                              \
        _Pragma("unroll")                                                         \
        for (int ni = 0; ni < 4; ++ni)                                            \
          acc[mi][ni] = __builtin_amdgcn_mfma_f32_16x16x32_bf16(af[mi], bfr[ni], acc[mi][ni], 0, 0, 0); \
    }

  STAGE_S(0, 0);
  __syncthreads();
  int cur = 0;
  for (int kt = 32; kt < K; kt += 32) {
    STAGE_S(cur ^ 1, kt);
    COMPUTE_S(cur);
    __syncthreads();
    cur ^= 1;
  }
  COMPUTE_S(cur);
  #undef STAGE_S
  #undef COMPUTE_S

  #pragma unroll
  for (int mi = 0; mi < 2; ++mi) {
    #pragma unroll
    for (int r = 0; r < 4; ++r) {
      int grow = row0 + wr + mi * 16 + kg * 4 + r;
      if (grow < M) {
        #pragma unroll
        for (int ni = 0; ni < 4; ++ni)
          C[(size_t)grow * Nc + col0 + wc + ni * 16 + lc] = acc[mi][ni][r];
      }
    }
  }
}

// ---------------- CSR scan (1024 threads); writes start[] and cursor[] ----------------
__global__ __launch_bounds__(1024) void scan_deg(const int* __restrict__ deg, int* __restrict__ start,
                                                 int* __restrict__ cursor, int N)
{
  __shared__ int sums[1024];
  int t = threadIdx.x;
  int chunk = (N + 1023) / 1024;
  int s = 0;
  for (int i = 0; i < chunk; ++i) {
    int idx = t * chunk + i;
    if (idx < N) s += deg[idx];
  }
  sums[t] = s;
  __syncthreads();
  for (int off = 1; off < 1024; off <<= 1) {
    int v = (t >= off) ? sums[t - off] : 0;
    __syncthreads();
    sums[t] += v;
    __syncthreads();
  }
  int run = (t == 0) ? 0 : sums[t - 1];
  for (int i = 0; i < chunk; ++i) {
    int idx = t * chunk + i;
    if (idx < N) { start[idx] = run; cursor[idx] = run; run += deg[idx]; }
  }
}

// fill buckets with SRC node id directly (removes ei indirection in gathers)
__global__ void fill_buckets(const int* __restrict__ ei, int* __restrict__ cursor,
                             int* __restrict__ srcs, int E)
{
  int e = blockIdx.x * 256 + threadIdx.x;
  if (e < E) {
    int n = ei[E + e];
    int p = atomicAdd(&cursor[n], 1);
    srcs[p] = ei[e];
  }
}

// ---------------- GAT per-dst softmax + aggregate (bf16 gather) -> x1 (bf16) ----------------
__global__ __launch_bounds__(256) void gat_aggregate(
    const ushort_t* __restrict__ hb, const float* __restrict__ a_src, const float* __restrict__ a_dst,
    const int* __restrict__ start, const int* __restrict__ deg,
    const int* __restrict__ srcs, const float* __restrict__ b_gat, ushort_t* __restrict__ x1,
    int N, int E)
{
  int n = blockIdx.x, t = threadIdx.x;
  __shared__ float adst[8];
  __shared__ float emax[8];
  __shared__ float esum[8];
  __shared__ float red[256];
  __shared__ float alpha_s[32][8];
  __shared__ int src_s[32];
  int cnt = deg[n];
  int base = start[n];
  if (t < 8) adst[t] = a_dst[n * 8 + t];
  __syncthreads();
  int hd = t & 7, lj = t >> 3;
  // phase A: per-head max
  float m = -1e30f;
  for (int j = lj; j < cnt; j += 32) {
    int s = srcs[base + j];
    float v = a_src[s * 8 + hd] + adst[hd];
    v = v > 0.f ? v : NEG_SLOPE * v;
    m = fmaxf(m, v);
  }
  red[t] = m;
  __syncthreads();
  #pragma unroll
  for (int off = 128; off >= 8; off >>= 1) {
    if (t < off) red[t] = fmaxf(red[t], red[t + off]);
    __syncthreads();
  }
  if (t < 8) emax[t] = red[t];
  __syncthreads();
  // phase B: per-head sum of exp
  float ssum = 0.f;
  for (int j = lj; j < cnt; j += 32) {
    int s = srcs[base + j];
    float v = a_src[s * 8 + hd] + adst[hd];
    v = v > 0.f ? v : NEG_SLOPE * v;
    ssum += expf(v - emax[hd]);
  }
  red[t] = ssum;
  __syncthreads();
  #pragma unroll
  for (int off = 128; off >= 8; off >>= 1) {
    if (t < off) red[t] += red[t + off];
    __syncthreads();
  }
  if (t < 8) esum[t] = red[t] + 1e-16f;
  __syncthreads();
  // phase C: thread t owns elements [t*8, t*8+8) -> head = t>>5 constant
  int head = t >> 5;
  float acc[8] = {0.f, 0.f, 0.f, 0.f, 0.f, 0.f, 0.f, 0.f};
  for (int j0 = 0; j0 < cnt; j0 += 32) {
    int j = j0 + lj;
    if (j < cnt) {
      int s = srcs[base + j];
      if (hd == 0) src_s[lj] = s;
      float v = a_src[s * 8 + hd] + adst[hd];
      v = v > 0.f ? v : NEG_SLOPE * v;
      alpha_s[lj][hd] = expf(v - emax[hd]) / esum[hd];
    }
    __syncthreads();
    int lim = cnt - j0; if (lim > 32) lim = 32;
    for (int el = 0; el < lim; ++el) {
      float al = alpha_s[el][head];
      u16x8 v = *(const u16x8*)(hb + (size_t)src_s[el] * GDIM + t * 8);
      #pragma unroll
      for (int i = 0; i < 8; ++i) acc[i] += bf2f(v[i]) * al;
    }
    __syncthreads();
  }
  u16x8 o;
  #pragma unroll
  for (int i = 0; i < 8; ++i) {
    float v = acc[i] + b_gat[t * 8 + i];
    o[i] = f2bf(v > 0.f ? v : 0.f);
  }
  *(u16x8*)(x1 + (size_t)n * GDIM + t * 8) = o;
}

// ---------------- SAGE: mean-aggregate y[:, :256][src] + y[:, 256:] + bias, relu -> x2 ----------------
__global__ __launch_bounds__(256) void sage_aggregate(
    const float* __restrict__ y, const int* __restrict__ start, const int* __restrict__ deg,
    const int* __restrict__ srcs, const float* __restrict__ b_l, float* __restrict__ x2,
    int N, int E)
{
  int w = threadIdx.x >> 6, lane = threadIdx.x & 63;
  int n = blockIdx.x * 4 + w;
  if (n >= N) return;
  int cnt = deg[n];
  int base = start[n];
  f32x4 acc = {0.f, 0.f, 0.f, 0.f};
  for (int j = 0; j < cnt; ++j) {
    int s = srcs[base + j];
    f32x4 v = *(const f32x4*)(y + (size_t)s * 512 + lane * 4);
    acc += v;
  }
  float d = (float)cnt; if (d < 1.f) d = 1.f;
  f32x4 root = *(const f32x4*)(y + (size_t)n * 512 + 256 + lane * 4);
  f32x4 b = *(const f32x4*)(b_l + lane * 4);
  f32x4 o;
  #pragma unroll
  for (int i = 0; i < 4; ++i) {
    float v = acc[i] / d + root[i] + b[i];
    o[i] = v > 0.f ? v : 0.f;
  }
  *(f32x4*)(x2 + (size_t)n * HID + lane * 4) = o;
}

// ---------------- MLP head, 16 nodes per block ----------------
__global__ __launch_bounds__(256) void mlp_head(
    const float* __restrict__ x2, const float* __restrict__ W1, const float* __restrict__ b1,
    const float* __restrict__ W2, const float* __restrict__ b2, float* __restrict__ out, int N)
{
  __shared__ float xs[16][256];
  __shared__ float wred[4][8];
  int t = threadIdx.x;
  int b0 = blockIdx.x * 16;
  for (int i = t; i < 16 * 64; i += 256) {
    int row = i >> 6, c4 = i & 63;
    int gr = b0 + row;
    f32x4 v = (gr < N) ? *(const f32x4*)(x2 + (size_t)gr * HID + c4 * 4)
                       : f32x4{0.f, 0.f, 0.f, 0.f};
    *(f32x4*)&xs[row][c4 * 4] = v;
  }
  __syncthreads();
  int c = t & 127, g = t >> 7;
  float acc[8];
  float bb = b1[c];
  #pragma unroll
  for (int nn = 0; nn < 8; ++nn) acc[nn] = bb;
  for (int k = 0; k < 256; ++k) {
    float w = W1[k * 128 + c];
    #pragma unroll
    for (int nn = 0; nn < 8; ++nn) acc[nn] += xs[g * 8 + nn][k] * w;
  }
  float w2 = W2[c];
  float p[8];
  #pragma unroll
  for (int nn = 0; nn < 8; ++nn) {
    float hm = acc[nn] > 0.f ? acc[nn] : 0.f;
    p[nn] = hm * w2;
  }
  #pragma unroll
  for (int off = 32; off >= 1; off >>= 1)
    #pragma unroll
    for (int nn = 0; nn < 8; ++nn) p[nn] += __shfl_down(p[nn], off);
  int wv = t >> 6;
  if ((t & 63) == 0) {
    #pragma unroll
    for (int nn = 0; nn < 8; ++nn) wred[wv][nn] = p[nn];
  }
  __syncthreads();
  if (t < 16) {
    int gg = t >> 3, nn = t & 7;
    int node = b0 + gg * 8 + nn;
    if (node < N)
      out[node] = wred[gg * 2][nn] + wred[gg * 2 + 1][nn] + b2[0];
  }
}

extern "C" void kernel_launch(void* const* d_in, const int* in_sizes, int n_in,
                              void* d_out, int out_size, void* d_ws, size_t ws_size,
                              hipStream_t stream)
{
  const float* x        = (const float*)d_in[0];
  const int*   ei       = (const int*)d_in[1];
  const float* W_gat    = (const float*)d_in[3];
  const float* att_src  = (const float*)d_in[4];
  const float* att_dst  = (const float*)d_in[5];
  const float* b_gat    = (const float*)d_in[6];
  const float* W_sage_l = (const float*)d_in[7];
  const float* b_sage_l = (const float*)d_in[8];
  const float* W_sage_r = (const float*)d_in[9];
  const float* W_lin1   = (const float*)d_in[10];
  const float* b_lin1   = (const float*)d_in[11];
  const float* W_lin2   = (const float*)d_in[12];
  const float* b_lin2   = (const float*)d_in[13];
  float* out = (float*)d_out;

  const int N = in_sizes[0] / INC;   // 10000
  const int E = in_sizes[1] / 2;     // 80000

  // ---- workspace carve ----
  char* p = (char*)d_ws;
  ushort_t* hb    = (ushort_t*)p;         p += (size_t)N * GDIM * 2;
  ushort_t* x1b   = (ushort_t*)p;         p += (size_t)N * GDIM * 2;
  float*    y     = (float*)p;            p += (size_t)N * 512 * 4;
  float*    x2    = (float*)p;            p += (size_t)N * HID * 4;
  ushort_t* xb    = (ushort_t*)p;         p += (size_t)N * INC * 2;
  ushort_t* WgatT = (ushort_t*)p;         p += (size_t)GDIM * INC * 2;
  ushort_t* WsT   = (ushort_t*)p;         p += (size_t)512 * GDIM * 2;
  float*    a_src = (float*)p;            p += (size_t)N * 8 * 4;
  float*    a_dst = (float*)p;            p += (size_t)N * 8 * 4;   // contiguous after a_src
  int*      deg   = (int*)p;              p += (size_t)N * 4;
  int*      start = (int*)p;              p += (size_t)N * 4;
  int*      cursor= (int*)p;              p += (size_t)N * 4;
  int*      srcs  = (int*)p;              p += (size_t)E * 4;

  hipMemsetAsync(deg, 0, (size_t)N * sizeof(int), stream);

  // 0) fused prep
  int nbX   = (N * INC + 1023) / 1024;           // x convert (exact multiple)
  int nbWg  = (INC / 32) * (GDIM / 32);
  int nbWs  = (GDIM / 32) * (HID / 32);
  int nbDeg = (E + 255) / 256;
  int nAZ   = N * 8 * 2;
  int nbZ   = (nAZ + 1023) / 1024;
  int o1 = nbX, o2 = o1 + nbWg, o3 = o2 + nbWs, o4 = o3 + nbWs, o5 = o4 + nbDeg;
  int nbTot = o5 + nbZ;
  prep<<<nbTot, 256, 0, stream>>>(x, xb, W_gat, WgatT, W_sage_l, W_sage_r, WsT,
                                  ei, deg, E, a_src, nAZ, o1, o2, o3, o4, o5);

  // CSR finish
  scan_deg<<<1, 1024, 0, stream>>>(deg, start, cursor, N);
  fill_buckets<<<(E + 255) / 256, 256, 0, stream>>>(ei, cursor, srcs, E);

  // 1) hb = bf16(x @ W_gat) with fused attention dots
  { dim3 grid((N + 127) / 128, GDIM / 128);
    gemm_gat<<<grid, 256, 0, stream>>>(xb, WgatT, hb, a_src, a_dst, att_src, att_dst,
                                       N, GDIM, INC); }

  // 2) GAT softmax-aggregate -> x1 (bf16)
  gat_aggregate<<<N, 256, 0, stream>>>(hb, a_src, a_dst, start, deg, srcs, b_gat, x1b, N, E);

  // 3) y = x1 @ [W_sage_l | W_sage_r]  (64x256 tile, 8 waves, dbuf)
  { dim3 grid((N + 63) / 64, 512 / 256);
    gemm_sage<<<grid, 512, 0, stream>>>(x1b, WsT, y, N, 512, GDIM); }

  // 4) SAGE mean aggregate + relu -> x2
  sage_aggregate<<<(N + 3) / 4, 256, 0, stream>>>(y, start, deg, srcs, b_sage_l, x2, N, E);

  // 5) MLP head -> out
  mlp_head<<<(N + 15) / 16, 256, 0, stream>>>(x2, W_lin1, b_lin1, W_lin2, b_lin2, out, N);
}

// Round 7
// 222.568 us; speedup vs baseline: 1.4257x; 1.0190x over previous
//
#include <hip/hip_runtime.h>
#include <math.h>

#define HEADS 8
#define HID 256
#define INC 128
#define GDIM 2048  // HEADS*HID
#define NEG_SLOPE 0.2f

typedef unsigned short ushort_t;
typedef short bf16x8 __attribute__((ext_vector_type(8)));
typedef ushort_t u16x8 __attribute__((ext_vector_type(8)));
typedef float f32x4 __attribute__((ext_vector_type(4)));

__device__ __forceinline__ ushort_t f2bf(float f) {
  union { float f; unsigned u; } v; v.f = f;
  unsigned r = (v.u + 0x7FFF + ((v.u >> 16) & 1)) >> 16;  // RTNE
  return (ushort_t)r;
}
__device__ __forceinline__ float bf2f(ushort_t u) {
  union { unsigned u; float f; } v; v.u = ((unsigned)u) << 16;
  return v.f;
}

__device__ __forceinline__ void gload_lds16(const ushort_t* g, ushort_t* l) {
  __builtin_amdgcn_global_load_lds(
      (const __attribute__((address_space(1))) unsigned int*)g,
      (__attribute__((address_space(3))) unsigned int*)l, 16, 0, 0);
}

// LDS chunk swizzle (verified r4/r5: SQ_LDS_BANK_CONFLICT -> 0)
__device__ __forceinline__ int src_chunk(int lane) {
  return ((lane & 3) - ((lane >> 3) & 3)) & 3;
}
__device__ __forceinline__ int rd_chunk(int lc, int kg) {
  return (kg + ((lc >> 1) & 3)) & 3;
}

// ---------------- fused prep: x->bf16, 3 weight transposes, deg_count, zero a ----------------
__global__ __launch_bounds__(256) void prep(
    const float* __restrict__ x, ushort_t* __restrict__ xb,
    const float* __restrict__ Wg, ushort_t* __restrict__ WgT,
    const float* __restrict__ Wl, const float* __restrict__ Wr, ushort_t* __restrict__ WsT,
    const int* __restrict__ ei, int* __restrict__ deg, int E,
    float* __restrict__ az, int nAZ,
    int o1, int o2, int o3, int o4, int o5)
{
  __shared__ float tile[32][33];
  int b = blockIdx.x, t = threadIdx.x;
  if (b < o1) {
    int i = b * 1024 + t * 4;
    float4 v = *(const float4*)(x + i);
    ushort_t o[4] = {f2bf(v.x), f2bf(v.y), f2bf(v.z), f2bf(v.w)};
    *(unsigned long long*)(xb + i) = *(unsigned long long*)o;
  } else if (b < o4) {
    const float* src; ushort_t* dst; int R, C, rowOff, bx, by;
    if (b < o2)      { int idx = b - o1; src = Wg; dst = WgT; R = INC;  C = GDIM; rowOff = 0;   bx = idx % (INC / 32);  by = idx / (INC / 32); }
    else if (b < o3) { int idx = b - o2; src = Wl; dst = WsT; R = GDIM; C = HID;  rowOff = 0;   bx = idx % (GDIM / 32); by = idx / (GDIM / 32); }
    else             { int idx = b - o3; src = Wr; dst = WsT; R = GDIM; C = HID;  rowOff = HID; bx = idx % (GDIM / 32); by = idx / (GDIM / 32); }
    int tx = t & 31, ty = t >> 5;
    int r0 = bx * 32, c0 = by * 32;
    #pragma unroll
    for (int i = 0; i < 32; i += 8)
      tile[ty + i][tx] = src[(size_t)(r0 + ty + i) * C + c0 + tx];
    __syncthreads();
    #pragma unroll
    for (int i = 0; i < 32; i += 8)
      dst[(size_t)(rowOff + c0 + ty + i) * R + r0 + tx] = f2bf(tile[tx][ty + i]);
  } else if (b < o5) {
    int e = (b - o4) * 256 + t;
    if (e < E) atomicAdd(&deg[ei[E + e]], 1);
  } else {
    int i = (b - o5) * 1024 + t * 4;
    if (i < nAZ) *(f32x4*)(az + i) = f32x4{0.f, 0.f, 0.f, 0.f};
  }
}

// ---------------- GAT GEMM: hb = bf16(x @ W_gat), fused attention dots ----------------
__global__ __launch_bounds__(256) void gemm_gat(
    const ushort_t* __restrict__ A, const ushort_t* __restrict__ BT,
    ushort_t* __restrict__ hb, float* __restrict__ a_src, float* __restrict__ a_dst,
    const float* __restrict__ att_s, const float* __restrict__ att_d,
    int M, int Nc, int K)
{
  __shared__ ushort_t As[2][128][32];
  __shared__ ushort_t Bs[2][128][32];
  int tid = threadIdx.x;
  int wave = tid >> 6, lane = tid & 63;
  int row0 = blockIdx.x * 128, col0 = blockIdx.y * 128;
  int wr = (wave >> 1) * 64, wc = (wave & 1) * 64;
  int lc = lane & 15, kg = lane >> 4;
  int sc = src_chunk(lane), srow = lane >> 2;

  f32x4 acc[4][4] = {};

  #define STAGE_G(buf, kt)                                                        \
    _Pragma("unroll")                                                             \
    for (int c = 0; c < 2; ++c) {                                                 \
      int r = c * 64 + wave * 16 + srow;                                          \
      int ga = row0 + r; if (ga >= M) ga = M - 1;                                 \
      gload_lds16(A + (size_t)ga * K + (kt) + sc * 8, &As[buf][c * 64 + wave * 16][0]); \
      int gb = col0 + r;                                                          \
      gload_lds16(BT + (size_t)gb * K + (kt) + sc * 8, &Bs[buf][c * 64 + wave * 16][0]); \
    }

  #define COMPUTE_G(buf)                                                          \
    {                                                                             \
      bf16x8 af[4], bfr[4];                                                       \
      _Pragma("unroll")                                                           \
      for (int mi = 0; mi < 4; ++mi)                                              \
        af[mi] = *(const bf16x8*)&As[buf][wr + mi * 16 + lc][rd_chunk(lc, kg) * 8]; \
      _Pragma("unroll")                                                           \
      for (int ni = 0; ni < 4; ++ni)                                              \
        bfr[ni] = *(const bf16x8*)&Bs[buf][wc + ni * 16 + lc][rd_chunk(lc, kg) * 8]; \
      _Pragma("unroll")                                                           \
      for (int mi = 0; mi < 4; ++mi)                                              \
        _Pragma("unroll")                                                         \
        for (int ni = 0; ni < 4; ++ni)                                            \
          acc[mi][ni] = __builtin_amdgcn_mfma_f32_16x16x32_bf16(af[mi], bfr[ni], acc[mi][ni], 0, 0, 0); \
    }

  STAGE_G(0, 0);
  __syncthreads();
  int cur = 0;
  for (int kt = 32; kt < K; kt += 32) {
    STAGE_G(cur ^ 1, kt);
    COMPUTE_G(cur);
    __syncthreads();
    cur ^= 1;
  }
  COMPUTE_G(cur);
  #undef STAGE_G
  #undef COMPUTE_G

  // epilogue: bf16 store + attention partial dots
  int head = (col0 + wc) >> 8;
  float as_v[4], ad_v[4];
  #pragma unroll
  for (int ni = 0; ni < 4; ++ni) {
    int gc = col0 + wc + ni * 16 + lc;
    as_v[ni] = att_s[gc];
    ad_v[ni] = att_d[gc];
  }
  #pragma unroll
  for (int mi = 0; mi < 4; ++mi) {
    #pragma unroll
    for (int r = 0; r < 4; ++r) {
      int grow = row0 + wr + mi * 16 + kg * 4 + r;
      float ps = 0.f, pd = 0.f;
      #pragma unroll
      for (int ni = 0; ni < 4; ++ni) {
        float v = acc[mi][ni][r];
        ps += v * as_v[ni];
        pd += v * ad_v[ni];
        if (grow < M) hb[(size_t)grow * Nc + col0 + wc + ni * 16 + lc] = f2bf(v);
      }
      #pragma unroll
      for (int off = 8; off >= 1; off >>= 1) {
        ps += __shfl_xor(ps, off);
        pd += __shfl_xor(pd, off);
      }
      if (lc == 0 && grow < M) {
        atomicAdd(&a_src[grow * 8 + head], ps);
        atomicAdd(&a_dst[grow * 8 + head], pd);
      }
    }
  }
}

// ---------------- SAGE GEMM: yb = bf16(A * BT^T), 64x256 tile, 8 waves, dbuf ----------------
__global__ __launch_bounds__(512) void gemm_sage(
    const ushort_t* __restrict__ A, const ushort_t* __restrict__ BT,
    ushort_t* __restrict__ C, int M, int Nc, int K)
{
  __shared__ ushort_t As[2][64][32];
  __shared__ ushort_t Bs[2][256][32];
  int tid = threadIdx.x;
  int wave = tid >> 6, lane = tid & 63;
  int row0 = blockIdx.x * 64, col0 = blockIdx.y * 256;
  int wr = (wave >> 2) * 32, wc = (wave & 3) * 64;
  int lc = lane & 15, kg = lane >> 4;
  int sc = src_chunk(lane), srow = lane >> 2;

  f32x4 acc[2][4] = {};

  #define STAGE_S(buf, kt)                                                        \
    {                                                                             \
      if (wave < 4) {                                                             \
        int ga = row0 + wave * 16 + srow; if (ga >= M) ga = M - 1;                \
        gload_lds16(A + (size_t)ga * K + (kt) + sc * 8, &As[buf][wave * 16][0]);  \
      }                                                                           \
      _Pragma("unroll")                                                           \
      for (int c = 0; c < 2; ++c) {                                               \
        int gb = col0 + c * 128 + wave * 16 + srow;                               \
        gload_lds16(BT + (size_t)gb * K + (kt) + sc * 8, &Bs[buf][c * 128 + wave * 16][0]); \
      }                                                                           \
    }

  #define COMPUTE_S(buf)                                                          \
    {                                                                             \
      bf16x8 af[2], bfr[4];                                                       \
      _Pragma("unroll")                                                           \
      for (int mi = 0; mi < 2; ++mi)                                              \
        af[mi] = *(const bf16x8*)&As[buf][wr + mi * 16 + lc][rd_chunk(lc, kg) * 8]; \
      _Pragma("unroll")                                                           \
      for (int ni = 0; ni < 4; ++ni)                                              \
        bfr[ni] = *(const bf16x8*)&Bs[buf][wc + ni * 16 + lc][rd_chunk(lc, kg) * 8]; \
      _Pragma("unroll")                                                           \
      for (int mi = 0; mi < 2; ++mi)                                              \
        _Pragma("unroll")                                                         \
        for (int ni = 0; ni < 4; ++ni)                                            \
          acc[mi][ni] = __builtin_amdgcn_mfma_f32_16x16x32_bf16(af[mi], bfr[ni], acc[mi][ni], 0, 0, 0); \
    }

  STAGE_S(0, 0);
  __syncthreads();
  int cur = 0;
  for (int kt = 32; kt < K; kt += 32) {
    STAGE_S(cur ^ 1, kt);
    COMPUTE_S(cur);
    __syncthreads();
    cur ^= 1;
  }
  COMPUTE_S(cur);
  #undef STAGE_S
  #undef COMPUTE_S

  #pragma unroll
  for (int mi = 0; mi < 2; ++mi) {
    #pragma unroll
    for (int r = 0; r < 4; ++r) {
      int grow = row0 + wr + mi * 16 + kg * 4 + r;
      if (grow < M) {
        #pragma unroll
        for (int ni = 0; ni < 4; ++ni)
          C[(size_t)grow * Nc + col0 + wc + ni * 16 + lc] = f2bf(acc[mi][ni][r]);
      }
    }
  }
}

// ---------------- CSR scan (1024 threads); writes start[] and cursor[] ----------------
__global__ __launch_bounds__(1024) void scan_deg(const int* __restrict__ deg, int* __restrict__ start,
                                                 int* __restrict__ cursor, int N)
{
  __shared__ int sums[1024];
  int t = threadIdx.x;
  int chunk = (N + 1023) / 1024;
  int s = 0;
  for (int i = 0; i < chunk; ++i) {
    int idx = t * chunk + i;
    if (idx < N) s += deg[idx];
  }
  sums[t] = s;
  __syncthreads();
  for (int off = 1; off < 1024; off <<= 1) {
    int v = (t >= off) ? sums[t - off] : 0;
    __syncthreads();
    sums[t] += v;
    __syncthreads();
  }
  int run = (t == 0) ? 0 : sums[t - 1];
  for (int i = 0; i < chunk; ++i) {
    int idx = t * chunk + i;
    if (idx < N) { start[idx] = run; cursor[idx] = run; run += deg[idx]; }
  }
}

// fill buckets with SRC node id directly
__global__ void fill_buckets(const int* __restrict__ ei, int* __restrict__ cursor,
                             int* __restrict__ srcs, int E)
{
  int e = blockIdx.x * 256 + threadIdx.x;
  if (e < E) {
    int n = ei[E + e];
    int p = atomicAdd(&cursor[n], 1);
    srcs[p] = ei[e];
  }
}

// ---------------- GAT per-dst softmax + aggregate (bf16 gather) -> x1 (bf16) ----------------
__global__ __launch_bounds__(256) void gat_aggregate(
    const ushort_t* __restrict__ hb, const float* __restrict__ a_src, const float* __restrict__ a_dst,
    const int* __restrict__ start, const int* __restrict__ deg,
    const int* __restrict__ srcs, const float* __restrict__ b_gat, ushort_t* __restrict__ x1,
    int N, int E)
{
  int n = blockIdx.x, t = threadIdx.x;
  __shared__ float adst[8];
  __shared__ float emax[8];
  __shared__ float esum[8];
  __shared__ float red[256];
  __shared__ float alpha_s[32][8];
  __shared__ int src_s[32];
  int cnt = deg[n];
  int base = start[n];
  if (t < 8) adst[t] = a_dst[n * 8 + t];
  __syncthreads();
  int hd = t & 7, lj = t >> 3;
  float m = -1e30f;
  for (int j = lj; j < cnt; j += 32) {
    int s = srcs[base + j];
    float v = a_src[s * 8 + hd] + adst[hd];
    v = v > 0.f ? v : NEG_SLOPE * v;
    m = fmaxf(m, v);
  }
  red[t] = m;
  __syncthreads();
  #pragma unroll
  for (int off = 128; off >= 8; off >>= 1) {
    if (t < off) red[t] = fmaxf(red[t], red[t + off]);
    __syncthreads();
  }
  if (t < 8) emax[t] = red[t];
  __syncthreads();
  float ssum = 0.f;
  for (int j = lj; j < cnt; j += 32) {
    int s = srcs[base + j];
    float v = a_src[s * 8 + hd] + adst[hd];
    v = v > 0.f ? v : NEG_SLOPE * v;
    ssum += expf(v - emax[hd]);
  }
  red[t] = ssum;
  __syncthreads();
  #pragma unroll
  for (int off = 128; off >= 8; off >>= 1) {
    if (t < off) red[t] += red[t + off];
    __syncthreads();
  }
  if (t < 8) esum[t] = red[t] + 1e-16f;
  __syncthreads();
  int head = t >> 5;
  float acc[8] = {0.f, 0.f, 0.f, 0.f, 0.f, 0.f, 0.f, 0.f};
  for (int j0 = 0; j0 < cnt; j0 += 32) {
    int j = j0 + lj;
    if (j < cnt) {
      int s = srcs[base + j];
      if (hd == 0) src_s[lj] = s;
      float v = a_src[s * 8 + hd] + adst[hd];
      v = v > 0.f ? v : NEG_SLOPE * v;
      alpha_s[lj][hd] = expf(v - emax[hd]) / esum[hd];
    }
    __syncthreads();
    int lim = cnt - j0; if (lim > 32) lim = 32;
    for (int el = 0; el < lim; ++el) {
      float al = alpha_s[el][head];
      u16x8 v = *(const u16x8*)(hb + (size_t)src_s[el] * GDIM + t * 8);
      #pragma unroll
      for (int i = 0; i < 8; ++i) acc[i] += bf2f(v[i]) * al;
    }
    __syncthreads();
  }
  u16x8 o;
  #pragma unroll
  for (int i = 0; i < 8; ++i) {
    float v = acc[i] + b_gat[t * 8 + i];
    o[i] = f2bf(v > 0.f ? v : 0.f);
  }
  *(u16x8*)(x1 + (size_t)n * GDIM + t * 8) = o;
}

// ---------------- fused SAGE aggregate + MLP head, 16 nodes per block ----------------
// yb: [N][512] bf16; cols 0-255 = x1@W_l (gathered over in-edges, mean),
// cols 256-511 = x1@W_r (root term).
__global__ __launch_bounds__(256) void sage_mlp(
    const ushort_t* __restrict__ yb, const int* __restrict__ start, const int* __restrict__ deg,
    const int* __restrict__ srcs, const float* __restrict__ b_l,
    const float* __restrict__ W1, const float* __restrict__ b1,
    const float* __restrict__ W2, const float* __restrict__ b2, float* __restrict__ out, int N)
{
  __shared__ float xs[16][256];   // 16 KB
  __shared__ float wred[4][8];
  int t = threadIdx.x;
  int wv = t >> 6, lane = t & 63;
  int b0 = blockIdx.x * 16;

  // phase 1: build 16 x2 rows in LDS (wave wv handles nodes wv*4 .. wv*4+3)
  int half = lane >> 5;        // 0: edge j, 1: edge j+1
  int col32 = lane & 31;       // covers cols col32*8 .. +8
  for (int i = 0; i < 4; ++i) {
    int nl = wv * 4 + i;
    int n = b0 + nl;
    float acc[8] = {0.f, 0.f, 0.f, 0.f, 0.f, 0.f, 0.f, 0.f};
    if (n < N) {
      int cnt = deg[n];
      int base = start[n];
      for (int j = 0; j < cnt; j += 2) {
        int jj = j + half;
        if (jj < cnt) {
          int s = srcs[base + jj];
          u16x8 v = *(const u16x8*)(yb + (size_t)s * 512 + col32 * 8);
          #pragma unroll
          for (int k = 0; k < 8; ++k) acc[k] += bf2f(v[k]);
        }
      }
      #pragma unroll
      for (int k = 0; k < 8; ++k) acc[k] += __shfl_xor(acc[k], 32);
      if (half == 0) {
        float d = (float)cnt; if (d < 1.f) d = 1.f;
        u16x8 r = *(const u16x8*)(yb + (size_t)n * 512 + 256 + col32 * 8);
        #pragma unroll
        for (int k = 0; k < 8; ++k) {
          float v = acc[k] / d + bf2f(r[k]) + b_l[col32 * 8 + k];
          xs[nl][col32 * 8 + k] = v > 0.f ? v : 0.f;
        }
      }
    } else if (half == 0) {
      #pragma unroll
      for (int k = 0; k < 8; ++k) xs[nl][col32 * 8 + k] = 0.f;
    }
  }
  __syncthreads();

  // phase 2: MLP (c = hidden unit, g selects node group of 8)
  int c = t & 127, g = t >> 7;
  float acc[8];
  float bb = b1[c];
  #pragma unroll
  for (int nn = 0; nn < 8; ++nn) acc[nn] = bb;
  for (int k = 0; k < 256; ++k) {
    float w = W1[k * 128 + c];
    #pragma unroll
    for (int nn = 0; nn < 8; ++nn) acc[nn] += xs[g * 8 + nn][k] * w;
  }
  float w2 = W2[c];
  float p[8];
  #pragma unroll
  for (int nn = 0; nn < 8; ++nn) {
    float hm = acc[nn] > 0.f ? acc[nn] : 0.f;
    p[nn] = hm * w2;
  }
  #pragma unroll
  for (int off = 32; off >= 1; off >>= 1)
    #pragma unroll
    for (int nn = 0; nn < 8; ++nn) p[nn] += __shfl_down(p[nn], off);
  if ((t & 63) == 0) {
    #pragma unroll
    for (int nn = 0; nn < 8; ++nn) wred[wv][nn] = p[nn];
  }
  __syncthreads();
  if (t < 16) {
    int gg = t >> 3, nn = t & 7;
    int node = b0 + gg * 8 + nn;
    if (node < N)
      out[node] = wred[gg * 2][nn] + wred[gg * 2 + 1][nn] + b2[0];
  }
}

extern "C" void kernel_launch(void* const* d_in, const int* in_sizes, int n_in,
                              void* d_out, int out_size, void* d_ws, size_t ws_size,
                              hipStream_t stream)
{
  const float* x        = (const float*)d_in[0];
  const int*   ei       = (const int*)d_in[1];
  const float* W_gat    = (const float*)d_in[3];
  const float* att_src  = (const float*)d_in[4];
  const float* att_dst  = (const float*)d_in[5];
  const float* b_gat    = (const float*)d_in[6];
  const float* W_sage_l = (const float*)d_in[7];
  const float* b_sage_l = (const float*)d_in[8];
  const float* W_sage_r = (const float*)d_in[9];
  const float* W_lin1   = (const float*)d_in[10];
  const float* b_lin1   = (const float*)d_in[11];
  const float* W_lin2   = (const float*)d_in[12];
  const float* b_lin2   = (const float*)d_in[13];
  float* out = (float*)d_out;

  const int N = in_sizes[0] / INC;   // 10000
  const int E = in_sizes[1] / 2;     // 80000

  // ---- workspace carve ----
  char* p = (char*)d_ws;
  ushort_t* hb    = (ushort_t*)p;         p += (size_t)N * GDIM * 2;
  ushort_t* x1b   = (ushort_t*)p;         p += (size_t)N * GDIM * 2;
  ushort_t* yb    = (ushort_t*)p;         p += (size_t)N * 512 * 2;
  ushort_t* xb    = (ushort_t*)p;         p += (size_t)N * INC * 2;
  ushort_t* WgatT = (ushort_t*)p;         p += (size_t)GDIM * INC * 2;
  ushort_t* WsT   = (ushort_t*)p;         p += (size_t)512 * GDIM * 2;
  float*    a_src = (float*)p;            p += (size_t)N * 8 * 4;
  float*    a_dst = (float*)p;            p += (size_t)N * 8 * 4;   // contiguous after a_src
  int*      deg   = (int*)p;              p += (size_t)N * 4;
  int*      start = (int*)p;              p += (size_t)N * 4;
  int*      cursor= (int*)p;              p += (size_t)N * 4;
  int*      srcs  = (int*)p;              p += (size_t)E * 4;

  hipMemsetAsync(deg, 0, (size_t)N * sizeof(int), stream);

  // 0) fused prep
  int nbX   = (N * INC + 1023) / 1024;
  int nbWg  = (INC / 32) * (GDIM / 32);
  int nbWs  = (GDIM / 32) * (HID / 32);
  int nbDeg = (E + 255) / 256;
  int nAZ   = N * 8 * 2;
  int nbZ   = (nAZ + 1023) / 1024;
  int o1 = nbX, o2 = o1 + nbWg, o3 = o2 + nbWs, o4 = o3 + nbWs, o5 = o4 + nbDeg;
  int nbTot = o5 + nbZ;
  prep<<<nbTot, 256, 0, stream>>>(x, xb, W_gat, WgatT, W_sage_l, W_sage_r, WsT,
                                  ei, deg, E, a_src, nAZ, o1, o2, o3, o4, o5);

  // CSR finish
  scan_deg<<<1, 1024, 0, stream>>>(deg, start, cursor, N);
  fill_buckets<<<(E + 255) / 256, 256, 0, stream>>>(ei, cursor, srcs, E);

  // 1) hb = bf16(x @ W_gat) with fused attention dots
  { dim3 grid((N + 127) / 128, GDIM / 128);
    gemm_gat<<<grid, 256, 0, stream>>>(xb, WgatT, hb, a_src, a_dst, att_src, att_dst,
                                       N, GDIM, INC); }

  // 2) GAT softmax-aggregate -> x1 (bf16)
  gat_aggregate<<<N, 256, 0, stream>>>(hb, a_src, a_dst, start, deg, srcs, b_gat, x1b, N, E);

  // 3) yb = bf16(x1 @ [W_sage_l | W_sage_r])  (64x256 tile, 8 waves, dbuf)
  { dim3 grid((N + 63) / 64, 512 / 256);
    gemm_sage<<<grid, 512, 0, stream>>>(x1b, WsT, yb, N, 512, GDIM); }

  // 4) fused SAGE mean-aggregate + MLP head -> out
  sage_mlp<<<(N + 15) / 16, 256, 0, stream>>>(yb, start, deg, srcs, b_sage_l,
                                              W_lin1, b_lin1, W_lin2, b_lin2, out, N);
}

// Round 8
// 181.042 us; speedup vs baseline: 1.7528x; 1.2294x over previous
//
#include <hip/hip_runtime.h>
#include <math.h>

#define HEADS 8
#define HID 256
#define INC 128
#define GDIM 2048  // HEADS*HID
#define NEG_SLOPE 0.2f

typedef unsigned short ushort_t;
typedef short bf16x8 __attribute__((ext_vector_type(8)));
typedef ushort_t u16x8 __attribute__((ext_vector_type(8)));
typedef float f32x4 __attribute__((ext_vector_type(4)));

__device__ __forceinline__ ushort_t f2bf(float f) {
  union { float f; unsigned u; } v; v.f = f;
  unsigned r = (v.u + 0x7FFF + ((v.u >> 16) & 1)) >> 16;  // RTNE
  return (ushort_t)r;
}
__device__ __forceinline__ float bf2f(ushort_t u) {
  union { unsigned u; float f; } v; v.u = ((unsigned)u) << 16;
  return v.f;
}

__device__ __forceinline__ void gload_lds16(const ushort_t* g, ushort_t* l) {
  __builtin_amdgcn_global_load_lds(
      (const __attribute__((address_space(1))) unsigned int*)g,
      (__attribute__((address_space(3))) unsigned int*)l, 16, 0, 0);
}

// LDS chunk swizzle (verified r4/r5: SQ_LDS_BANK_CONFLICT -> 0)
__device__ __forceinline__ int src_chunk(int lane) {
  return ((lane & 3) - ((lane >> 3) & 3)) & 3;
}
__device__ __forceinline__ int rd_chunk(int lc, int kg) {
  return (kg + ((lc >> 1) & 3)) & 3;
}

// ---------------- fused prep: x->bf16, 3 weight transposes, deg_count, wtilde ----------------
// wtilde: wt[j][k] = sum_c W_gat[k][hd*256+c] * att[hd][c], j=hd (src) or 8+hd (dst)
__global__ __launch_bounds__(256) void prep(
    const float* __restrict__ x, ushort_t* __restrict__ xb,
    const float* __restrict__ Wg, ushort_t* __restrict__ WgT,
    const float* __restrict__ Wl, const float* __restrict__ Wr, ushort_t* __restrict__ WsT,
    const int* __restrict__ ei, int* __restrict__ deg, int E,
    const float* __restrict__ att_s, const float* __restrict__ att_d, float* __restrict__ wt,
    int o1, int o2, int o3, int o4, int o5)
{
  __shared__ float tile[32][33];
  __shared__ float attl[256];
  int b = blockIdx.x, t = threadIdx.x;
  if (b < o1) {
    int i = b * 1024 + t * 4;
    float4 v = *(const float4*)(x + i);
    ushort_t o[4] = {f2bf(v.x), f2bf(v.y), f2bf(v.z), f2bf(v.w)};
    *(unsigned long long*)(xb + i) = *(unsigned long long*)o;
  } else if (b < o4) {
    const float* src; ushort_t* dst; int R, C, rowOff, bx, by;
    if (b < o2)      { int idx = b - o1; src = Wg; dst = WgT; R = INC;  C = GDIM; rowOff = 0;   bx = idx % (INC / 32);  by = idx / (INC / 32); }
    else if (b < o3) { int idx = b - o2; src = Wl; dst = WsT; R = GDIM; C = HID;  rowOff = 0;   bx = idx % (GDIM / 32); by = idx / (GDIM / 32); }
    else             { int idx = b - o3; src = Wr; dst = WsT; R = GDIM; C = HID;  rowOff = HID; bx = idx % (GDIM / 32); by = idx / (GDIM / 32); }
    int tx = t & 31, ty = t >> 5;
    int r0 = bx * 32, c0 = by * 32;
    #pragma unroll
    for (int i = 0; i < 32; i += 8)
      tile[ty + i][tx] = src[(size_t)(r0 + ty + i) * C + c0 + tx];
    __syncthreads();
    #pragma unroll
    for (int i = 0; i < 32; i += 8)
      dst[(size_t)(rowOff + c0 + ty + i) * R + r0 + tx] = f2bf(tile[tx][ty + i]);
  } else if (b < o5) {
    int e = (b - o4) * 256 + t;
    if (e < E) atomicAdd(&deg[ei[E + e]], 1);
  } else {
    int j = b - o5;                 // 0..15
    int hd = j & 7;
    const float* att = (j < 8) ? att_s : att_d;
    if (t < 256) attl[t] = att[hd * 256 + t];
    __syncthreads();
    if (t < 128) {
      float acc = 0.f;
      #pragma unroll 8
      for (int c = 0; c < 256; ++c)
        acc += Wg[(size_t)t * GDIM + hd * 256 + c] * attl[c];
      wt[j * 128 + t] = acc;
    }
  }
}

// ---------------- a_all[n][16] = xb[n] . wt[j]  (j<8: src dots, j>=8: dst dots) ----------------
__global__ __launch_bounds__(256) void a_dots(
    const ushort_t* __restrict__ xb, const float* __restrict__ wt,
    float* __restrict__ a_all, int N)
{
  __shared__ float wts[16][132];   // padded: (j,j+8) 2-way alias only
  __shared__ ushort_t xs[16 * 128];
  int t = threadIdx.x;
  for (int i = t; i < 2048; i += 256) wts[i >> 7][i & 127] = wt[i];
  int b0 = blockIdx.x * 16;
  {
    int row = t >> 4, off = (t & 15) * 8;
    int n = b0 + row; if (n >= N) n = N - 1;
    *(u16x8*)&xs[row * 128 + off] = *(const u16x8*)(xb + (size_t)n * 128 + off);
  }
  __syncthreads();
  int nl = t >> 4, j = t & 15;
  float acc = 0.f;
  #pragma unroll 8
  for (int k = 0; k < 128; ++k)
    acc += bf2f(xs[nl * 128 + k]) * wts[j][k];
  int n = b0 + nl;
  if (n < N) a_all[(size_t)n * 16 + j] = acc;
}

// ---------------- CSR scan (1024 threads); writes start[] and cursor[] ----------------
__global__ __launch_bounds__(1024) void scan_deg(const int* __restrict__ deg, int* __restrict__ start,
                                                 int* __restrict__ cursor, int N)
{
  __shared__ int sums[1024];
  int t = threadIdx.x;
  int chunk = (N + 1023) / 1024;
  int s = 0;
  for (int i = 0; i < chunk; ++i) {
    int idx = t * chunk + i;
    if (idx < N) s += deg[idx];
  }
  sums[t] = s;
  __syncthreads();
  for (int off = 1; off < 1024; off <<= 1) {
    int v = (t >= off) ? sums[t - off] : 0;
    __syncthreads();
    sums[t] += v;
    __syncthreads();
  }
  int run = (t == 0) ? 0 : sums[t - 1];
  for (int i = 0; i < chunk; ++i) {
    int idx = t * chunk + i;
    if (idx < N) { start[idx] = run; cursor[idx] = run; run += deg[idx]; }
  }
}

__global__ void fill_buckets(const int* __restrict__ ei, int* __restrict__ cursor,
                             int* __restrict__ srcs, int E)
{
  int e = blockIdx.x * 256 + threadIdx.x;
  if (e < E) {
    int n = ei[E + e];
    int p = atomicAdd(&cursor[n], 1);
    srcs[p] = ei[e];
  }
}

// ---------------- GAT softmax + x-space aggregate -> aggb[N][8][128] bf16 ----------------
__global__ __launch_bounds__(256) void gat_aggregate(
    const ushort_t* __restrict__ xb, const float* __restrict__ a_all,
    const int* __restrict__ start, const int* __restrict__ deg,
    const int* __restrict__ srcs, ushort_t* __restrict__ aggb, int N)
{
  int n = blockIdx.x, t = threadIdx.x;
  __shared__ float adst[8];
  __shared__ float emax[8];
  __shared__ float esum[8];
  __shared__ float red[256];
  __shared__ float alpha_s[32][8];
  __shared__ int src_s[32];
  int cnt = deg[n];
  int base = start[n];
  if (t < 8) adst[t] = a_all[(size_t)n * 16 + 8 + t];
  __syncthreads();
  int hd = t & 7, lj = t >> 3;
  // phase A: per-head max of leakyrelu(a_src[s]+a_dst[n])
  float m = -1e30f;
  for (int j = lj; j < cnt; j += 32) {
    int s = srcs[base + j];
    float v = a_all[(size_t)s * 16 + hd] + adst[hd];
    v = v > 0.f ? v : NEG_SLOPE * v;
    m = fmaxf(m, v);
  }
  red[t] = m;
  __syncthreads();
  #pragma unroll
  for (int off = 128; off >= 8; off >>= 1) {
    if (t < off) red[t] = fmaxf(red[t], red[t + off]);
    __syncthreads();
  }
  if (t < 8) emax[t] = red[t];
  __syncthreads();
  // phase B: per-head sum of exp
  float ssum = 0.f;
  for (int j = lj; j < cnt; j += 32) {
    int s = srcs[base + j];
    float v = a_all[(size_t)s * 16 + hd] + adst[hd];
    v = v > 0.f ? v : NEG_SLOPE * v;
    ssum += expf(v - emax[hd]);
  }
  red[t] = ssum;
  __syncthreads();
  #pragma unroll
  for (int off = 128; off >= 8; off >>= 1) {
    if (t < off) red[t] += red[t + off];
    __syncthreads();
  }
  if (t < 8) esum[t] = red[t] + 1e-16f;
  __syncthreads();
  // phase C: gather x rows (256B) and accumulate per-head weighted sums.
  // thread t: dim d = t&127, head group hg = t>>7 (heads hg*4..hg*4+3)
  int d = t & 127, hg = t >> 7;
  float acc[4] = {0.f, 0.f, 0.f, 0.f};
  for (int j0 = 0; j0 < cnt; j0 += 32) {
    int j = j0 + lj;
    if (j < cnt) {
      int s = srcs[base + j];
      if (hd == 0) src_s[lj] = s;
      float v = a_all[(size_t)s * 16 + hd] + adst[hd];
      v = v > 0.f ? v : NEG_SLOPE * v;
      alpha_s[lj][hd] = expf(v - emax[hd]) / esum[hd];
    }
    __syncthreads();
    int lim = cnt - j0; if (lim > 32) lim = 32;
    for (int el = 0; el < lim; ++el) {
      float v = bf2f(xb[(size_t)src_s[el] * INC + d]);
      #pragma unroll
      for (int k = 0; k < 4; ++k) acc[k] += v * alpha_s[el][hg * 4 + k];
    }
    __syncthreads();
  }
  #pragma unroll
  for (int k = 0; k < 4; ++k)
    aggb[(size_t)n * 1024 + (hg * 4 + k) * INC + d] = f2bf(acc[k]);
}

// ---------------- per-head GEMM: x1 = relu(agg_hd @ W_hd + b_gat), 128x128 tile ----------------
// A = aggb [N][1024] (per-head K=128 slice), BT = WgatT (row c: W_gat[:,c], 128 bf16)
__global__ __launch_bounds__(256) void gemm_gat(
    const ushort_t* __restrict__ A, const ushort_t* __restrict__ BT,
    const float* __restrict__ b_gat, ushort_t* __restrict__ x1, int M)
{
  __shared__ ushort_t As[2][128][32];
  __shared__ ushort_t Bs[2][128][32];
  int tid = threadIdx.x;
  int wave = tid >> 6, lane = tid & 63;
  int row0 = blockIdx.x * 128;
  int head = blockIdx.y >> 1, colblk = blockIdx.y & 1;
  const ushort_t* Abase = A + head * INC;                         // row stride 1024
  const ushort_t* Bbase = BT + ((size_t)head * 256 + colblk * 128) * INC;
  int wr = (wave >> 1) * 64, wc = (wave & 1) * 64;
  int lc = lane & 15, kg = lane >> 4;
  int sc = src_chunk(lane), srow = lane >> 2;

  f32x4 acc[4][4] = {};

  #define STAGE_G(buf, kt)                                                        \
    _Pragma("unroll")                                                             \
    for (int c = 0; c < 2; ++c) {                                                 \
      int r = c * 64 + wave * 16 + srow;                                          \
      int ga = row0 + r; if (ga >= M) ga = M - 1;                                 \
      gload_lds16(Abase + (size_t)ga * 1024 + (kt) + sc * 8, &As[buf][c * 64 + wave * 16][0]); \
      gload_lds16(Bbase + (size_t)r * INC + (kt) + sc * 8, &Bs[buf][c * 64 + wave * 16][0]); \
    }

  #define COMPUTE_G(buf)                                                          \
    {                                                                             \
      bf16x8 af[4], bfr[4];                                                       \
      _Pragma("unroll")                                                           \
      for (int mi = 0; mi < 4; ++mi)                                              \
        af[mi] = *(const bf16x8*)&As[buf][wr + mi * 16 + lc][rd_chunk(lc, kg) * 8]; \
      _Pragma("unroll")                                                           \
      for (int ni = 0; ni < 4; ++ni)                                              \
        bfr[ni] = *(const bf16x8*)&Bs[buf][wc + ni * 16 + lc][rd_chunk(lc, kg) * 8]; \
      _Pragma("unroll")                                                           \
      for (int mi = 0; mi < 4; ++mi)                                              \
        _Pragma("unroll")                                                         \
        for (int ni = 0; ni < 4; ++ni)                                            \
          acc[mi][ni] = __builtin_amdgcn_mfma_f32_16x16x32_bf16(af[mi], bfr[ni], acc[mi][ni], 0, 0, 0); \
    }

  STAGE_G(0, 0);
  __syncthreads();
  int cur = 0;
  for (int kt = 32; kt < INC; kt += 32) {
    STAGE_G(cur ^ 1, kt);
    COMPUTE_G(cur);
    __syncthreads();
    cur ^= 1;
  }
  COMPUTE_G(cur);
  #undef STAGE_G
  #undef COMPUTE_G

  int gcol0 = head * 256 + colblk * 128;
  float bg[4];
  #pragma unroll
  for (int ni = 0; ni < 4; ++ni) bg[ni] = b_gat[gcol0 + wc + ni * 16 + lc];
  #pragma unroll
  for (int mi = 0; mi < 4; ++mi) {
    #pragma unroll
    for (int r = 0; r < 4; ++r) {
      int grow = row0 + wr + mi * 16 + kg * 4 + r;
      if (grow < M) {
        #pragma unroll
        for (int ni = 0; ni < 4; ++ni) {
          float v = acc[mi][ni][r] + bg[ni];
          x1[(size_t)grow * GDIM + gcol0 + wc + ni * 16 + lc] = f2bf(v > 0.f ? v : 0.f);
        }
      }
    }
  }
}

// ---------------- SAGE GEMM: yb = bf16(A * BT^T), 64x256 tile, 8 waves, dbuf ----------------
__global__ __launch_bounds__(512) void gemm_sage(
    const ushort_t* __restrict__ A, const ushort_t* __restrict__ BT,
    ushort_t* __restrict__ C, int M, int Nc, int K)
{
  __shared__ ushort_t As[2][64][32];
  __shared__ ushort_t Bs[2][256][32];
  int tid = threadIdx.x;
  int wave = tid >> 6, lane = tid & 63;
  int row0 = blockIdx.x * 64, col0 = blockIdx.y * 256;
  int wr = (wave >> 2) * 32, wc = (wave & 3) * 64;
  int lc = lane & 15, kg = lane >> 4;
  int sc = src_chunk(lane), srow = lane >> 2;

  f32x4 acc[2][4] = {};

  #define STAGE_S(buf, kt)                                                        \
    {                                                                             \
      if (wave < 4) {                                                             \
        int ga = row0 + wave * 16 + srow; if (ga >= M) ga = M - 1;                \
        gload_lds16(A + (size_t)ga * K + (kt) + sc * 8, &As[buf][wave * 16][0]);  \
      }                                                                           \
      _Pragma("unroll")                                                           \
      for (int c = 0; c < 2; ++c) {                                               \
        int gb = col0 + c * 128 + wave * 16 + srow;                               \
        gload_lds16(BT + (size_t)gb * K + (kt) + sc * 8, &Bs[buf][c * 128 + wave * 16][0]); \
      }                                                                           \
    }

  #define COMPUTE_S(buf)                                                          \
    {                                                                             \
      bf16x8 af[2], bfr[4];                                                       \
      _Pragma("unroll")                                                           \
      for (int mi = 0; mi < 2; ++mi)                                              \
        af[mi] = *(const bf16x8*)&As[buf][wr + mi * 16 + lc][rd_chunk(lc, kg) * 8]; \
      _Pragma("unroll")                                                           \
      for (int ni = 0; ni < 4; ++ni)                                              \
        bfr[ni] = *(const bf16x8*)&Bs[buf][wc + ni * 16 + lc][rd_chunk(lc, kg) * 8]; \
      _Pragma("unroll")                                                           \
      for (int mi = 0; mi < 2; ++mi)                                              \
        _Pragma("unroll")                                                         \
        for (int ni = 0; ni < 4; ++ni)                                            \
          acc[mi][ni] = __builtin_amdgcn_mfma_f32_16x16x32_bf16(af[mi], bfr[ni], acc[mi][ni], 0, 0, 0); \
    }

  STAGE_S(0, 0);
  __syncthreads();
  int cur = 0;
  for (int kt = 32; kt < K; kt += 32) {
    STAGE_S(cur ^ 1, kt);
    COMPUTE_S(cur);
    __syncthreads();
    cur ^= 1;
  }
  COMPUTE_S(cur);
  #undef STAGE_S
  #undef COMPUTE_S

  #pragma unroll
  for (int mi = 0; mi < 2; ++mi) {
    #pragma unroll
    for (int r = 0; r < 4; ++r) {
      int grow = row0 + wr + mi * 16 + kg * 4 + r;
      if (grow < M) {
        #pragma unroll
        for (int ni = 0; ni < 4; ++ni)
          C[(size_t)grow * Nc + col0 + wc + ni * 16 + lc] = f2bf(acc[mi][ni][r]);
      }
    }
  }
}

// ---------------- fused SAGE aggregate + MLP head, 16 nodes per block ----------------
__global__ __launch_bounds__(256) void sage_mlp(
    const ushort_t* __restrict__ yb, const int* __restrict__ start, const int* __restrict__ deg,
    const int* __restrict__ srcs, const float* __restrict__ b_l,
    const float* __restrict__ W1, const float* __restrict__ b1,
    const float* __restrict__ W2, const float* __restrict__ b2, float* __restrict__ out, int N)
{
  __shared__ float xs[16][256];
  __shared__ float wred[4][8];
  int t = threadIdx.x;
  int wv = t >> 6, lane = t & 63;
  int b0 = blockIdx.x * 16;

  int half = lane >> 5;
  int col32 = lane & 31;
  for (int i = 0; i < 4; ++i) {
    int nl = wv * 4 + i;
    int n = b0 + nl;
    float acc[8] = {0.f, 0.f, 0.f, 0.f, 0.f, 0.f, 0.f, 0.f};
    if (n < N) {
      int cnt = deg[n];
      int base = start[n];
      for (int j = 0; j < cnt; j += 2) {
        int jj = j + half;
        if (jj < cnt) {
          int s = srcs[base + jj];
          u16x8 v = *(const u16x8*)(yb + (size_t)s * 512 + col32 * 8);
          #pragma unroll
          for (int k = 0; k < 8; ++k) acc[k] += bf2f(v[k]);
        }
      }
      #pragma unroll
      for (int k = 0; k < 8; ++k) acc[k] += __shfl_xor(acc[k], 32);
      if (half == 0) {
        float d = (float)cnt; if (d < 1.f) d = 1.f;
        u16x8 r = *(const u16x8*)(yb + (size_t)n * 512 + 256 + col32 * 8);
        #pragma unroll
        for (int k = 0; k < 8; ++k) {
          float v = acc[k] / d + bf2f(r[k]) + b_l[col32 * 8 + k];
          xs[nl][col32 * 8 + k] = v > 0.f ? v : 0.f;
        }
      }
    } else if (half == 0) {
      #pragma unroll
      for (int k = 0; k < 8; ++k) xs[nl][col32 * 8 + k] = 0.f;
    }
  }
  __syncthreads();

  int c = t & 127, g = t >> 7;
  float acc[8];
  float bb = b1[c];
  #pragma unroll
  for (int nn = 0; nn < 8; ++nn) acc[nn] = bb;
  for (int k = 0; k < 256; ++k) {
    float w = W1[k * 128 + c];
    #pragma unroll
    for (int nn = 0; nn < 8; ++nn) acc[nn] += xs[g * 8 + nn][k] * w;
  }
  float w2 = W2[c];
  float p[8];
  #pragma unroll
  for (int nn = 0; nn < 8; ++nn) {
    float hm = acc[nn] > 0.f ? acc[nn] : 0.f;
    p[nn] = hm * w2;
  }
  #pragma unroll
  for (int off = 32; off >= 1; off >>= 1)
    #pragma unroll
    for (int nn = 0; nn < 8; ++nn) p[nn] += __shfl_down(p[nn], off);
  if ((t & 63) == 0) {
    #pragma unroll
    for (int nn = 0; nn < 8; ++nn) wred[wv][nn] = p[nn];
  }
  __syncthreads();
  if (t < 16) {
    int gg = t >> 3, nn = t & 7;
    int node = b0 + gg * 8 + nn;
    if (node < N)
      out[node] = wred[gg * 2][nn] + wred[gg * 2 + 1][nn] + b2[0];
  }
}

extern "C" void kernel_launch(void* const* d_in, const int* in_sizes, int n_in,
                              void* d_out, int out_size, void* d_ws, size_t ws_size,
                              hipStream_t stream)
{
  const float* x        = (const float*)d_in[0];
  const int*   ei       = (const int*)d_in[1];
  const float* W_gat    = (const float*)d_in[3];
  const float* att_src  = (const float*)d_in[4];
  const float* att_dst  = (const float*)d_in[5];
  const float* b_gat    = (const float*)d_in[6];
  const float* W_sage_l = (const float*)d_in[7];
  const float* b_sage_l = (const float*)d_in[8];
  const float* W_sage_r = (const float*)d_in[9];
  const float* W_lin1   = (const float*)d_in[10];
  const float* b_lin1   = (const float*)d_in[11];
  const float* W_lin2   = (const float*)d_in[12];
  const float* b_lin2   = (const float*)d_in[13];
  float* out = (float*)d_out;

  const int N = in_sizes[0] / INC;   // 10000
  const int E = in_sizes[1] / 2;     // 80000

  // ---- workspace carve ----
  char* p = (char*)d_ws;
  ushort_t* x1b   = (ushort_t*)p;         p += (size_t)N * GDIM * 2;   // 41 MB
  ushort_t* aggb  = (ushort_t*)p;         p += (size_t)N * 1024 * 2;   // 20 MB
  ushort_t* yb    = (ushort_t*)p;         p += (size_t)N * 512 * 2;    // 10 MB
  ushort_t* xb    = (ushort_t*)p;         p += (size_t)N * INC * 2;    // 2.6 MB
  ushort_t* WgatT = (ushort_t*)p;         p += (size_t)GDIM * INC * 2; // 0.5 MB
  ushort_t* WsT   = (ushort_t*)p;         p += (size_t)512 * GDIM * 2; // 2 MB
  float*    wt    = (float*)p;            p += (size_t)16 * 128 * 4;
  float*    a_all = (float*)p;            p += (size_t)N * 16 * 4;
  int*      deg   = (int*)p;              p += (size_t)N * 4;
  int*      start = (int*)p;              p += (size_t)N * 4;
  int*      cursor= (int*)p;              p += (size_t)N * 4;
  int*      srcs  = (int*)p;              p += (size_t)E * 4;

  hipMemsetAsync(deg, 0, (size_t)N * sizeof(int), stream);

  // 0) fused prep
  int nbX   = (N * INC + 1023) / 1024;
  int nbWg  = (INC / 32) * (GDIM / 32);
  int nbWs  = (GDIM / 32) * (HID / 32);
  int nbDeg = (E + 255) / 256;
  int o1 = nbX, o2 = o1 + nbWg, o3 = o2 + nbWs, o4 = o3 + nbWs, o5 = o4 + nbDeg;
  int nbTot = o5 + 16;   // 16 wtilde blocks
  prep<<<nbTot, 256, 0, stream>>>(x, xb, W_gat, WgatT, W_sage_l, W_sage_r, WsT,
                                  ei, deg, E, att_src, att_dst, wt, o1, o2, o3, o4, o5);

  // CSR finish
  scan_deg<<<1, 1024, 0, stream>>>(deg, start, cursor, N);
  fill_buckets<<<(E + 255) / 256, 256, 0, stream>>>(ei, cursor, srcs, E);

  // 1) attention logits a_all[n][16]
  a_dots<<<(N + 15) / 16, 256, 0, stream>>>(xb, wt, a_all, N);

  // 2) GAT softmax + x-space aggregate -> aggb
  gat_aggregate<<<N, 256, 0, stream>>>(xb, a_all, start, deg, srcs, aggb, N);

  // 3) per-head GEMM: x1 = relu(agg @ W_hd + b_gat)
  { dim3 grid((N + 127) / 128, 16);
    gemm_gat<<<grid, 256, 0, stream>>>(aggb, WgatT, b_gat, x1b, N); }

  // 4) yb = bf16(x1 @ [W_sage_l | W_sage_r])
  { dim3 grid((N + 63) / 64, 512 / 256);
    gemm_sage<<<grid, 512, 0, stream>>>(x1b, WsT, yb, N, 512, GDIM); }

  // 5) fused SAGE mean-aggregate + MLP head -> out
  sage_mlp<<<(N + 15) / 16, 256, 0, stream>>>(yb, start, deg, srcs, b_sage_l,
                                              W_lin1, b_lin1, W_lin2, b_lin2, out, N);
}